// Round 5
// baseline (357.530 us; speedup 1.0000x reference)
//
#include <hip/hip_runtime.h>
#include <hip/hip_fp16.h>
#include <cstdint>
#include <cstddef>

// ---------------------------------------------------------------------------
// TopoGNN: 3x SAGEConv(mean) + BN + ReLU, softmax-attention pooling, 2 heads.
// N=100000 nodes, E=1600000 edges, B=64 segments, IN_CH=6, HID=64.
// R5 (754us) bucket-CSR. R7 (644us) bn_pool. R8 (593us) split matmul+BN-fly.
// R9 (529us) fp16 rows. R12 (474us) MFMA GEMM. R15 (409us) stats 64-slot.
// R17/R19 (381us) group-per-node fp8 gather. R20 (373us) agg fused into MFMA.
// R21 (361us) dispatch merge 19->15. R22 (357us) raw h fp16.
// R23 (766us REGRESSION): per-block __threadfence = L2 writeback x2587 ->
//     h8/h16 evicted, agg FETCH 77.5MB. LESSON: no device fences in
//     cache-resident gather kernels.
// R24 (341us): fence-free merges only (prep+hist, csr_local+sage1).
// R25: (1) h16 stream eliminated — GEMM self-term decoded from h8 row
//     (fp8->f16 exact per value; self-term now fp8-quantized). Saves the
//     12.8MB h16 write x2 and halves the agg self read; agg hot set
//     19.2->6.4MB (better per-XCD L2 residency for the random gather).
//     (2) stats_reduce x2 folded into consumers' prologues (bn_dual L2/L3,
//     bn_pool): 32KB statsTmp is L2-hot broadcast; removes two 1-block
//     serialization bubbles. 12 dispatches.
// ---------------------------------------------------------------------------

#define EPB 8192   // edges per partition block (256 thr x 32)
#define NBIN 512   // padded bucket count (actual NB = ceil(N/256) <= 512)
#define EPS_BN 1e-5f

typedef _Float16 f16x8 __attribute__((ext_vector_type(8)));
typedef float    f32x4 __attribute__((ext_vector_type(4)));
typedef float    f32x2 __attribute__((ext_vector_type(2)));

// fp8x8 (two dwords) -> 8 halves; e4m3 -> f32 -> f16 is exact.
static __device__ inline f16x8 fp8x8_to_h8(uint2 r)
{
    f32x2 a0 = __builtin_amdgcn_cvt_pk_f32_fp8(r.x, false);
    f32x2 a1 = __builtin_amdgcn_cvt_pk_f32_fp8(r.x, true);
    f32x2 b0 = __builtin_amdgcn_cvt_pk_f32_fp8(r.y, false);
    f32x2 b1 = __builtin_amdgcn_cvt_pk_f32_fp8(r.y, true);
    f16x8 o;
    o[0] = (_Float16)a0[0]; o[1] = (_Float16)a0[1];
    o[2] = (_Float16)a1[0]; o[3] = (_Float16)a1[1];
    o[4] = (_Float16)b0[0]; o[5] = (_Float16)b0[1];
    o[6] = (_Float16)b1[0]; o[7] = (_Float16)b1[1];
    return o;
}

// ---- merged: per-block bucket histogram (bid < nBlk) + prep roles --------
//      prep: softmax denom (pbid 0-255), seg_bounds (256), w_prep (257-320).
__global__ __launch_bounds__(256) void prep_hist(
    const int* __restrict__ dst, int* __restrict__ blockBin,
    int* __restrict__ binTotal, int E, int nBlk,
    const float* __restrict__ x, float* __restrict__ sumexp, int n,
    const int* __restrict__ batch, int* __restrict__ lb,
    const float* __restrict__ W2l, const float* __restrict__ W2r,
    const float* __restrict__ W3l, const float* __restrict__ W3r,
    __half* __restrict__ wfrag2, __half* __restrict__ wfrag3)
{
    __shared__ int hist[NBIN];
    __shared__ float wsum[4];
    int t = threadIdx.x;
    int bid = blockIdx.x;
    if (bid < nBlk) {
        for (int i = t; i < NBIN; i += 256) hist[i] = 0;
        __syncthreads();
        int e0 = bid * EPB;
#pragma unroll
        for (int k = 0; k < 32; k++) {
            int e = e0 + (k << 8) + t;
            if (e < E) atomicAdd(&hist[dst[e] >> 8], 1);
        }
        __syncthreads();
        for (int i = t; i < NBIN; i += 256) {
            int c = hist[i];
            blockBin[bid * NBIN + i] = c;
            if (c) atomicAdd(&binTotal[i], c);
        }
        return;
    }
    int pbid = bid - nBlk;
    if (pbid < 256) {
        float s = 0.f;
        int stride = 256 * 256;
        for (int i = pbid * 256 + t; i < n; i += stride)
            s += expf(x[(size_t)i * 6 + 4]);
#pragma unroll
        for (int o = 32; o > 0; o >>= 1) s += __shfl_down(s, o, 64);
        if ((t & 63) == 0) wsum[t >> 6] = s;
        __syncthreads();
        if (t == 0)
            unsafeAtomicAdd(sumexp, wsum[0] + wsum[1] + wsum[2] + wsum[3]);
    } else if (pbid == 256) {
        int b = t;
        if (b > 64) return;
        int lo = 0, hi = n;
        while (lo < hi) {
            int mid = (lo + hi) >> 1;
            if (batch[mid] < b) lo = mid + 1; else hi = mid;
        }
        lb[b] = lo;
    } else {
        bool second = (pbid >= 289);
        int i = (pbid - (second ? 289 : 257)) * 256 + t;
        if (i >= 8192) return;
        int j    = i & 7;
        int m    = (i >> 3) & 15;
        int quad = (i >> 7) & 3;
        int tt   = (i >> 9) & 3;
        int q    = i >> 11;
        int k    = (q & 1) * 32 + quad * 8 + j;
        int col  = tt * 16 + m;
        const float* W = second ? ((q < 2) ? W3l : W3r)
                                : ((q < 2) ? W2l : W2r);
        (second ? wfrag3 : wfrag2)[i] = __float2half_rn(W[k * 64 + col]);
    }
}

// ---- phase B (merged): per-block redundant scan of bin totals + per-bin
//      exclusive scan over block counts. 64 blocks x 512 threads (8 waves).
//      Block 0 publishes binBase[0..NBIN] and rowptr[N]=E.
__global__ __launch_bounds__(512) void blockbin_offs(int* __restrict__ blockBin,
                                                     const int* __restrict__ binTotal,
                                                     int* __restrict__ binBase,
                                                     int* __restrict__ rowptrN,
                                                     int nBlk)
{
    __shared__ int s[NBIN];
    int t = threadIdx.x;
    int tot = binTotal[t];
    s[t] = tot;
    __syncthreads();
    for (int off = 1; off < NBIN; off <<= 1) {
        int v = (t >= off) ? s[t - off] : 0;
        __syncthreads();
        s[t] += v;
        __syncthreads();
    }
    int excl = s[t] - tot;
    if (blockIdx.x == 0) {
        binBase[t] = excl;
        if (t == NBIN - 1) { binBase[NBIN] = s[t]; *rowptrN = s[t]; }
    }
    __syncthreads();

    int wv   = t >> 6;              // 0..7
    int lane = t & 63;
    int bin  = blockIdx.x * 8 + wv;
    int carry = s[bin] - binTotal[bin];   // exclusive base for this bin
    for (int c0 = 0; c0 < nBlk; c0 += 64) {
        int blk = c0 + lane;
        int cnt = (blk < nBlk) ? blockBin[blk * NBIN + bin] : 0;
        int v = cnt;
#pragma unroll
        for (int d = 1; d < 64; d <<= 1) {
            int u = __shfl_up(v, d, 64);
            if (lane >= d) v += u;
        }
        if (blk < nBlk) blockBin[blk * NBIN + bin] = carry + v - cnt;
        carry += __shfl(v, 63, 64);
    }
}

// ---- phase C: place packed (src | local_dst<<24); per-block LDS cursors ---
__global__ __launch_bounds__(256) void bucket_scatter(const int* __restrict__ src,
                                                      const int* __restrict__ dst,
                                                      const int* __restrict__ blockBin,
                                                      int* __restrict__ epck, int E)
{
    __shared__ int cur[NBIN];
    int t = threadIdx.x;
    for (int i = t; i < NBIN; i += 256) cur[i] = blockBin[blockIdx.x * NBIN + i];
    __syncthreads();
    int e0 = blockIdx.x * EPB;
#pragma unroll
    for (int k = 0; k < 32; k++) {
        int e = e0 + (k << 8) + t;
        if (e < E) {
            int d = dst[e];
            int pos = atomicAdd(&cur[d >> 8], 1);
            epck[pos] = src[e] | ((d & 255) << 24);   // src < 2^24
        }
    }
}

// ---- merged phase D + layer 1: per-bucket local CSR, then fused
//      pull-aggregation (6 ch) + matmul for the same 256 nodes.
//      Edge ranges come from the in-LDS scan (no global rowptr read);
//      eidx re-read after __syncthreads hits own-XCD L2. No fences.
__global__ __launch_bounds__(256) void csr_sage1(
    const int* __restrict__ epck, const int* __restrict__ binBase,
    int* __restrict__ rowptr, int* __restrict__ eidx,
    const float* __restrict__ x,
    const float* __restrict__ Wl, const float* __restrict__ bias,
    const float* __restrict__ Wr, __half* __restrict__ out, int N)
{
    __shared__ int cnt[256], s[256], cur[256];
    __shared__ float4 sWl[6 * 16];
    __shared__ float4 sWr[6 * 16];
    int t = threadIdx.x, bkt = blockIdx.x;
    for (int i = t; i < 6 * 16; i += 256) {
        sWl[i] = ((const float4*)Wl)[i];
        sWr[i] = ((const float4*)Wr)[i];
    }
    int base = binBase[bkt], nE = binBase[bkt + 1] - base;
    cnt[t] = 0;
    __syncthreads();
    for (int j = t; j < nE; j += 256)
        atomicAdd(&cnt[(unsigned)epck[base + j] >> 24], 1);
    __syncthreads();
    s[t] = cnt[t];
    __syncthreads();
    for (int off = 1; off < 256; off <<= 1) {
        int v = (t >= off) ? s[t - off] : 0;
        __syncthreads();
        s[t] += v;
        __syncthreads();
    }
    int excl = s[t] - cnt[t];
    cur[t] = excl;
    int node = (bkt << 8) + t;
    if (node < N) rowptr[node] = base + excl;
    __syncthreads();
    for (int j = t; j < nE; j += 256) {
        int v = epck[base + j];
        int pos = atomicAdd(&cur[(unsigned)v >> 24], 1);
        eidx[base + pos] = v & 0xFFFFFF;     // contiguous 16KB span: stays in L2
    }
    __syncthreads();    // eidx writes drained to L2 before re-read

    // ---- sage1 part: this block's nodes == this bucket ----
    if (node >= N) return;
    int eb = base + excl, ee = base + s[t];
    float a[6] = {0.f, 0.f, 0.f, 0.f, 0.f, 0.f};
    for (int j = eb; j < ee; j++) {
        int si = eidx[j];
        const float2* r = (const float2*)(x + (size_t)si * 6);
        float2 r0 = r[0], r1 = r[1], r2 = r[2];
        a[0] += r0.x; a[1] += r0.y; a[2] += r1.x;
        a[3] += r1.y; a[4] += r2.x; a[5] += r2.y;
    }
    float invd = 1.0f / fmaxf((float)(ee - eb), 1.0f);

    const float2* xr2 = (const float2*)(x + (size_t)node * 6);
    float2 x0 = xr2[0], x1 = xr2[1], x2 = xr2[2];
    float hh[6] = {x0.x, x0.y, x1.x, x1.y, x2.x, x2.y};

    float4 acc[16];
#pragma unroll
    for (int cg = 0; cg < 16; cg++) acc[cg] = ((const float4*)bias)[cg];
#pragma unroll
    for (int k = 0; k < 6; k++) {
        float am = a[k] * invd;
        float hk = hh[k];
#pragma unroll
        for (int cg = 0; cg < 16; cg++) {
            float4 wl = sWl[k * 16 + cg];
            float4 wr = sWr[k * 16 + cg];
            acc[cg].x = fmaf(am, wl.x, fmaf(hk, wr.x, acc[cg].x));
            acc[cg].y = fmaf(am, wl.y, fmaf(hk, wr.y, acc[cg].y));
            acc[cg].z = fmaf(am, wl.z, fmaf(hk, wr.z, acc[cg].z));
            acc[cg].w = fmaf(am, wl.w, fmaf(hk, wr.w, acc[cg].w));
        }
    }
    __half* orow = out + (size_t)node * 64;
#pragma unroll
    for (int cg = 0; cg < 8; cg++) {
        float4 a0 = acc[2 * cg], a1 = acc[2 * cg + 1];
        float4 o;
        ((__half2*)&o)[0] = __floats2half2_rn(a0.x, a0.y);
        ((__half2*)&o)[1] = __floats2half2_rn(a0.z, a0.w);
        ((__half2*)&o)[2] = __floats2half2_rn(a1.x, a1.y);
        ((__half2*)&o)[3] = __floats2half2_rn(a1.z, a1.w);
        ((float4*)orow)[cg] = o;
    }
}

// ---- BN stats (separate pass — layer 1 only). fp16 input, 8 ch/thr ------
__global__ __launch_bounds__(256) void bn_stats(const __half* __restrict__ h,
                                                float* __restrict__ stats, size_t nchunk)
{
    __shared__ float ls[64], lss[64];
    int t = threadIdx.x;
    if (t < 64) { ls[t] = 0.f; lss[t] = 0.f; }
    __syncthreads();
    float s[8]  = {0.f, 0.f, 0.f, 0.f, 0.f, 0.f, 0.f, 0.f};
    float ss[8] = {0.f, 0.f, 0.f, 0.f, 0.f, 0.f, 0.f, 0.f};
    size_t stride = (size_t)gridDim.x * 256;
    for (size_t i = (size_t)blockIdx.x * 256 + t; i < nchunk; i += stride) {
        float4 hv = ((const float4*)h)[i];
        const __half2* hp = (const __half2*)&hv;
#pragma unroll
        for (int j = 0; j < 4; j++) {
            float2 f = __half22float2(hp[j]);
            s[2 * j]     += f.x;
            ss[2 * j]     = fmaf(f.x, f.x, ss[2 * j]);
            s[2 * j + 1] += f.y;
            ss[2 * j + 1] = fmaf(f.y, f.y, ss[2 * j + 1]);
        }
    }
    int c0 = (t & 7) * 8;     // chunk stride is a multiple of 8 chunks
#pragma unroll
    for (int j = 0; j < 8; j++) {
        atomicAdd(&ls[c0 + j], s[j]);
        atomicAdd(&lss[c0 + j], ss[j]);
    }
    __syncthreads();
    if (t < 64) {
        unsafeAtomicAdd(&stats[t], ls[t]);
        unsafeAtomicAdd(&stats[64 + t], lss[t]);
    }
}

// ---- bn_dual: v = relu(bn(h)); h8 = fp8(v) (all GEMM operands now fp8).
//      nSlots>0: statsIn = 64-slot scratch, reduced in prologue (L2-hot).
__global__ __launch_bounds__(256) void bn_dual(const __half* __restrict__ h,
                                               const float* __restrict__ statsIn,
                                               int nSlots,
                                               const float* __restrict__ g,
                                               const float* __restrict__ be,
                                               unsigned* __restrict__ h8,
                                               float invN, size_t nchunk)
{
    __shared__ float sst[128];
    __shared__ float ssc[64], ssh[64];
    int t = threadIdx.x;
    if (nSlots) {
        if (t < 128) {
            float s = 0.f;
            for (int k = 0; k < nSlots; k++) s += statsIn[(size_t)k * 128 + t];
            sst[t] = s;
        }
    } else if (t < 128) {
        sst[t] = statsIn[t];
    }
    __syncthreads();
    if (t < 64) {
        float mu  = sst[t] * invN;
        float var = sst[64 + t] * invN - mu * mu;
        float sc  = g[t] / sqrtf(var + EPS_BN);
        ssc[t] = sc;
        ssh[t] = fmaf(-mu, sc, be[t]);
    }
    __syncthreads();
    size_t i8 = (size_t)blockIdx.x * 256 + t;
    if (i8 >= nchunk) return;
    int c0 = (int)((i8 * 8) & 63);
    float4 hv = ((const float4*)h)[i8];
    const __half2* hp = (const __half2*)&hv;
    float v[8];
#pragma unroll
    for (int j = 0; j < 4; j++) {
        float2 f = __half22float2(hp[j]);
        v[2 * j] = f.x;
        v[2 * j + 1] = f.y;
    }
#pragma unroll
    for (int j = 0; j < 8; j++) {
        int c = c0 + j;
        v[j] = fmaxf(fmaf(v[j], ssc[c], ssh[c]), 0.f);
    }
    int p0 = __builtin_amdgcn_cvt_pk_fp8_f32(v[0], v[1], 0, false);
    p0     = __builtin_amdgcn_cvt_pk_fp8_f32(v[2], v[3], p0, true);
    int p1 = __builtin_amdgcn_cvt_pk_fp8_f32(v[4], v[5], 0, false);
    p1     = __builtin_amdgcn_cvt_pk_fp8_f32(v[6], v[7], p1, true);
    uint2 pk;
    pk.x = (unsigned)p0;
    pk.y = (unsigned)p1;
    ((uint2*)h8)[i8] = pk;
}

// ---- fused aggregation + MFMA GEMM + BN stats. Self-term from h8 (R25). --
#define TSTRIDE 72
__global__ __launch_bounds__(256) void agg_mm_mfma(
    const int* __restrict__ rowptr, const int* __restrict__ eidx,
    const unsigned* __restrict__ h8,
    const __half* __restrict__ wfh, const float* __restrict__ bias,
    __half* __restrict__ out, float* __restrict__ statsTmp, int n)
{
    __shared__ float ls[64], lss[64];
    __shared__ _Float16 sT[4][16 * TSTRIDE];   // 4 waves x 16 nodes x 64ch
    int t = threadIdx.x;
    if (t < 64) { ls[t] = 0.f; lss[t] = 0.f; }

    int wv = t >> 6, lane = t & 63;
    int node0 = (blockIdx.x * 4 + wv) * 16;

    // ---- gather phase ----
    int grp = lane >> 4, cq = lane & 15;
#pragma unroll 1
    for (int r = 0; r < 4; r++) {
        int node = node0 + r * 4 + grp;
        int b = 0, e = 0;
        if (node < n) { b = rowptr[node]; e = rowptr[node + 1]; }

        float4 a0 = {0,0,0,0}, a1 = {0,0,0,0}, a2 = {0,0,0,0}, a3 = {0,0,0,0};
#define EDGE(S, ACC)                                                            \
        {                                                                       \
            unsigned r_ = h8[(size_t)(S) * 16 + cq];                            \
            f32x2 lo_ = __builtin_amdgcn_cvt_pk_f32_fp8(r_, false);             \
            f32x2 hi_ = __builtin_amdgcn_cvt_pk_f32_fp8(r_, true);              \
            ACC.x += lo_[0]; ACC.y += lo_[1]; ACC.z += hi_[0]; ACC.w += hi_[1]; \
        }
        int j = b;
        for (; j + 4 <= e; j += 4) {
            int s0 = eidx[j], s1 = eidx[j + 1], s2 = eidx[j + 2], s3 = eidx[j + 3];
            EDGE(s0, a0) EDGE(s1, a1) EDGE(s2, a2) EDGE(s3, a3)
        }
        for (; j < e; j++) {
            int s = eidx[j];
            EDGE(s, a0)
        }
#undef EDGE
        float ax = a0.x + a1.x + a2.x + a3.x;
        float ay = a0.y + a1.y + a2.y + a3.y;
        float az = a0.z + a1.z + a2.z + a3.z;
        float aw = a0.w + a1.w + a2.w + a3.w;
        float invd = 1.0f / fmaxf((float)(e - b), 1.0f);
        __half2 o01 = __floats2half2_rn(ax * invd, ay * invd);
        __half2 o23 = __floats2half2_rn(az * invd, aw * invd);
        float2 ov;
        ((__half2*)&ov)[0] = o01;
        ((__half2*)&ov)[1] = o23;
        *(float2*)(&sT[wv][(r * 4 + grp) * TSTRIDE + cq * 4]) = ov;
    }
    __syncthreads();    // drains LDS writes (also covers ls/lss init)

    // ---- GEMM phase ----
    int m = lane & 15, quad = lane >> 4;
    if (node0 < n) {
        const f16x8* wf = (const f16x8*)wfh;   // frag idx ((q*4+tt)*4+quad)*16+m

        int nodeA = node0 + m;
        if (nodeA >= n) nodeA = n - 1;         // tail-safe global loads

        const uint2* hrow8 = (const uint2*)(h8 + (size_t)nodeA * 16);
        uint2 rlo = hrow8[quad];               // channels quad*8 .. +7
        uint2 rhi = hrow8[4 + quad];           // channels 32+quad*8 .. +7
        f16x8 af[4];
        af[0] = *(const f16x8*)(&sT[wv][m * TSTRIDE + quad * 8]);
        af[1] = *(const f16x8*)(&sT[wv][m * TSTRIDE + 32 + quad * 8]);
        af[2] = fp8x8_to_h8(rlo);
        af[3] = fp8x8_to_h8(rhi);

#pragma unroll
        for (int tt = 0; tt < 4; tt++) {
            float bv = bias[tt * 16 + m];
            f32x4 c = {bv, bv, bv, bv};
#pragma unroll
            for (int q = 0; q < 4; q++)
                c = __builtin_amdgcn_mfma_f32_16x16x32_f16(
                        af[q], wf[((q * 4 + tt) * 4 + quad) * 16 + m], c, 0, 0, 0);
            float s = 0.f, ss = 0.f;
#pragma unroll
            for (int r = 0; r < 4; r++) {
                int row = node0 + quad * 4 + r;
                float v = (row < n) ? c[r] : 0.f;
                if (row < n) out[(size_t)row * 64 + tt * 16 + m] = __float2half_rn(v);
                s += v;
                ss = fmaf(v, v, ss);
            }
            s  += __shfl_xor(s, 16, 64);  s  += __shfl_xor(s, 32, 64);
            ss += __shfl_xor(ss, 16, 64); ss += __shfl_xor(ss, 32, 64);
            if (quad == 0) {
                atomicAdd(&ls[tt * 16 + m], s);
                atomicAdd(&lss[tt * 16 + m], ss);
            }
        }
    }
    __syncthreads();
    if (t < 64) {
        float* slot = statsTmp + (size_t)(blockIdx.x & 63) * 128;
        unsafeAtomicAdd(&slot[t], ls[t]);
        unsafeAtomicAdd(&slot[64 + t], lss[t]);
    }
}

// ---- fused layer-3 BN+ReLU + attention pooling; stats from 64-slot
//      scratch reduced in prologue (replaces stats_reduce dispatch). ------
__global__ __launch_bounds__(256) void bn_pool(
    const __half* __restrict__ h, const float* __restrict__ statsTmp,
    const float* __restrict__ g, const float* __restrict__ be,
    const float* __restrict__ x, const int* __restrict__ batch,
    float* __restrict__ rawpool, float invN, int N, int chunk)
{
    __shared__ float sst[128];
    int t = threadIdx.x;
    if (t < 128) {
        float s = 0.f;
        for (int k = 0; k < 64; k++) s += statsTmp[(size_t)k * 128 + t];
        sst[t] = s;
    }
    __syncthreads();

    int wid  = blockIdx.x * 4 + (t >> 6);
    int lane = t & 63;
    int i0 = wid * chunk;
    if (i0 >= N) return;
    int i1 = min(i0 + chunk, N);

    float mu  = sst[lane] * invN;
    float var = sst[64 + lane] * invN - mu * mu;
    float sc  = g[lane] / sqrtf(var + EPS_BN);
    float sh  = fmaf(-mu, sc, be[lane]);

    int   cur = batch[i0];
    float acc = 0.f;
    for (int i = i0; i < i1; i++) {
        int bi = batch[i];
        if (bi != cur) {
            unsafeAtomicAdd(&rawpool[cur * 64 + lane], acc);
            acc = 0.f;
            cur = bi;
        }
        float w = expf(x[(size_t)i * 6 + 4]);
        float v = fmaxf(fmaf(__half2float(h[(size_t)i * 64 + lane]), sc, sh), 0.f);
        acc = fmaf(v, w, acc);
    }
    unsafeAtomicAdd(&rawpool[cur * 64 + lane], acc);
}

// ---- heads: normalize rawpool by 1/sumexp and counts, then 2 tiny MLPs ----
__global__ __launch_bounds__(64) void heads_kernel(
    const float* __restrict__ rawpool, const float* __restrict__ sumexp,
    const int* __restrict__ lb,
    const float* __restrict__ phW1, const float* __restrict__ phb1,
    const float* __restrict__ phW2, const float* __restrict__ phb2,
    const float* __restrict__ trW1, const float* __restrict__ trb1,
    const float* __restrict__ trW2, const float* __restrict__ trb2,
    float* __restrict__ out)
{
    int b = blockIdx.x, t = threadIdx.x;
    __shared__ float p[64], h1[32], h2[16];
    float cnt = (float)(lb[b + 1] - lb[b]);
    p[t] = rawpool[b * 64 + t] / (sumexp[0] * fmaxf(cnt, 1.0f));
    __syncthreads();
    if (t < 32) {
        float s = phb1[t];
        for (int k = 0; k < 64; k++) s = fmaf(p[k], phW1[k * 32 + t], s);
        h1[t] = fmaxf(s, 0.f);
    } else if (t < 48) {
        int tt = t - 32;
        float s = trb1[tt];
        for (int k = 0; k < 64; k++) s = fmaf(p[k], trW1[k * 16 + tt], s);
        h2[tt] = fmaxf(s, 0.f);
    }
    __syncthreads();
    if (t < 3) {
        float s = phb2[t];
        for (int k = 0; k < 32; k++) s = fmaf(h1[k], phW2[k * 3 + t], s);
        out[b * 3 + t] = s;
    } else if (t == 63) {
        float s = trb2[0];
        for (int k = 0; k < 16; k++) s = fmaf(h2[k], trW2[k], s);
        out[192 + b] = 1.0f / (1.0f + expf(-s));
    }
}

extern "C" void kernel_launch(void* const* d_in, const int* in_sizes, int n_in,
                              void* d_out, int out_size, void* d_ws, size_t ws_size,
                              hipStream_t stream)
{
    const float* x     = (const float*)d_in[0];
    const int*   ei    = (const int*)d_in[1];
    const int*   batch = (const int*)d_in[2];
    const float* W1l = (const float*)d_in[3];
    const float* b1  = (const float*)d_in[4];
    const float* W1r = (const float*)d_in[5];
    const float* W2l = (const float*)d_in[6];
    const float* b2  = (const float*)d_in[7];
    const float* W2r = (const float*)d_in[8];
    const float* W3l = (const float*)d_in[9];
    const float* b3  = (const float*)d_in[10];
    const float* W3r = (const float*)d_in[11];
    const float* g1  = (const float*)d_in[12];
    const float* be1 = (const float*)d_in[13];
    const float* g2  = (const float*)d_in[14];
    const float* be2 = (const float*)d_in[15];
    const float* g3  = (const float*)d_in[16];
    const float* be3 = (const float*)d_in[17];
    const float* phW1 = (const float*)d_in[18];
    const float* phb1 = (const float*)d_in[19];
    const float* phW2 = (const float*)d_in[20];
    const float* phb2 = (const float*)d_in[21];
    const float* trW1 = (const float*)d_in[22];
    const float* trb1 = (const float*)d_in[23];
    const float* trW2 = (const float*)d_in[24];
    const float* trb2 = (const float*)d_in[25];

    const int N = in_sizes[0] / 6;
    const int E = in_sizes[1] / 2;
    const int* src = ei;
    const int* dst = ei + E;

    const int NB    = (N + 255) >> 8;          // 391 buckets
    const int nBlkA = (E + EPB - 1) / EPB;     // 196 partition blocks

    float* ws = (float*)d_ws;
    const size_t N64 = (size_t)N * 64;
    float*  hA      = ws;                          // N*64 region (fp16 raw h1/h3)
    float*  hB      = ws + N64;                    // N*64 region (fp16 raw h2)
    // (h16 region retired in R25 — layout offsets kept)
    int*   epck     = (int*)(ws + 3 * N64);        // E packed src|dl<<24
    int*   eidx     = epck + E;                    // E (CSR by dst)
    int*   blockBin = eidx + E;                    // nBlkA * NBIN
    // --- contiguous zero region: binTotal + stats + statsTmp + rawpool + sumexp
    int*   binTotal = blockBin + (size_t)nBlkA * NBIN;   // NBIN
    float* stats    = (float*)(binTotal + NBIN);   // 3 * 128
    float* statsTmp = stats + 384;                 // 2 * 64 * 128
    float* rawpool  = statsTmp + 16384;            // 64*64
    float* sumexp   = rawpool + 4096;              // 1 (pad 4)
    // --- end zero region ---
    int*   binBase  = (int*)(sumexp + 4);          // NBIN + 1
    int*   rowptr   = binBase + NBIN + 1;          // N + 1
    int*   lb       = rowptr + N + 1;              // 65 (pad 72)
    __half* wfrag2  = (__half*)(lb + 72);          // 8192 fp16
    __half* wfrag3  = wfrag2 + 8192;               // 8192 fp16
    unsigned* h8    = (unsigned*)(wfrag3 + 8192);  // N*16 dwords (fp8 rows)
    float* out      = (float*)d_out;

    const int mfmaBlocks = (N + 63) / 64;          // 1563 (4 x 16-node tiles/block)
    const size_t nchunk  = N64 / 8;                // 8-half chunks (N64 % 8 == 0)
    const int cvt8Blocks = (int)((nchunk + 255) / 256);
    const int PBLK = 1024;                         // bn_pool blocks (4 waves each)
    const int chunk = (N + PBLK * 4 - 1) / (PBLK * 4);
    const float invN = 1.0f / (float)N;

    // ---- zero accumulators; merged prep+hist ----
    size_t zbytes = (char*)(sumexp + 4) - (char*)binTotal;
    hipMemsetAsync(binTotal, 0, zbytes, stream);
    prep_hist<<<nBlkA + 321, 256, 0, stream>>>(dst, blockBin, binTotal, E, nBlkA,
                                               x, sumexp, N, batch, lb,
                                               W2l, W2r, W3l, W3r, wfrag2, wfrag3);

    // ---- CSR build (scan merged into blockbin_offs) ----
    blockbin_offs<<<NBIN / 8, 512, 0, stream>>>(blockBin, binTotal, binBase,
                                                rowptr + N, nBlkA);
    bucket_scatter<<<nBlkA, 256, 0, stream>>>(src, dst, blockBin, epck, E);

    // ---- merged CSR-local + layer 1 ----
    csr_sage1<<<NB, 256, 0, stream>>>(epck, binBase, rowptr, eidx,
                                      x, W1l, b1, W1r, (__half*)hA, N);
    bn_stats<<<1024, 256, 0, stream>>>((const __half*)hA, stats, nchunk);
    bn_dual<<<cvt8Blocks, 256, 0, stream>>>((const __half*)hA, stats, 0, g1, be1,
                                            h8, invN, nchunk);

    // ---- layer 2 (fused gather+GEMM -> hB; stats2 -> 64-slot scratch) ----
    agg_mm_mfma<<<mfmaBlocks, 256, 0, stream>>>(rowptr, eidx, h8, wfrag2, b2,
                                                (__half*)hB, statsTmp, N);
    bn_dual<<<cvt8Blocks, 256, 0, stream>>>((const __half*)hB, statsTmp, 64,
                                            g2, be2, h8, invN, nchunk);

    // ---- layer 3 (fused gather+GEMM -> hA; stats3 -> 64-slot scratch) ----
    agg_mm_mfma<<<mfmaBlocks, 256, 0, stream>>>(rowptr, eidx, h8, wfrag3, b3,
                                                (__half*)hA, statsTmp + 8192, N);

    // ---- fused BN3 + attention pooling (stats reduced in prologue) ----
    bn_pool<<<PBLK, 256, 0, stream>>>((const __half*)hA, statsTmp + 8192, g3, be3,
                                      x, batch, rawpool, invN, N, chunk);
    heads_kernel<<<64, 64, 0, stream>>>(rawpool, sumexp, lb,
                                        phW1, phb1, phW2, phb2,
                                        trW1, trb1, trW2, trb2, out);
}

// Round 6
// 339.018 us; speedup vs baseline: 1.0546x; 1.0546x over previous
//
#include <hip/hip_runtime.h>
#include <hip/hip_fp16.h>
#include <cstdint>
#include <cstddef>

// ---------------------------------------------------------------------------
// TopoGNN: 3x SAGEConv(mean) + BN + ReLU, softmax-attention pooling, 2 heads.
// N=100000 nodes, E=1600000 edges, B=64 segments, IN_CH=6, HID=64.
// R5 (754us) bucket-CSR. R7 (644us) bn_pool. R8 (593us) split matmul+BN-fly.
// R9 (529us) fp16 rows. R12 (474us) MFMA GEMM. R15 (409us) stats 64-slot.
// R17/R19 (381us) group-per-node fp8 gather. R20 (373us) agg fused into MFMA.
// R21 (361us) dispatch merge 19->15. R22 (357us) raw h fp16.
// R23 (766us REGRESSION): per-block __threadfence evicts L2 -> lesson.
// R24 (341us): fence-free merges only (prep+hist, csr_local+sage1).
// R25 (357us REGRESSION, bundled): h16-elim + stats prologue folding.
//     Arithmetic says h16-elim is ~-5us, prologue-fold ~0/-; unbundling.
// R26: R24 + h16-elim ONLY. stats_reduce dispatches restored; bn_dual
//     writes h8 only; agg self-term decoded from own h8 row (fp8->f16
//     exact). A/B vs R24: if ~357 the h16-elim is the true regression.
// ---------------------------------------------------------------------------

#define EPB 8192   // edges per partition block (256 thr x 32)
#define NBIN 512   // padded bucket count (actual NB = ceil(N/256) <= 512)
#define EPS_BN 1e-5f

typedef _Float16 f16x8 __attribute__((ext_vector_type(8)));
typedef float    f32x4 __attribute__((ext_vector_type(4)));
typedef float    f32x2 __attribute__((ext_vector_type(2)));

// fp8x8 (two dwords) -> 8 halves; e4m3 -> f32 -> f16 is exact.
static __device__ inline f16x8 fp8x8_to_h8(uint2 r)
{
    f32x2 a0 = __builtin_amdgcn_cvt_pk_f32_fp8(r.x, false);
    f32x2 a1 = __builtin_amdgcn_cvt_pk_f32_fp8(r.x, true);
    f32x2 b0 = __builtin_amdgcn_cvt_pk_f32_fp8(r.y, false);
    f32x2 b1 = __builtin_amdgcn_cvt_pk_f32_fp8(r.y, true);
    f16x8 o;
    o[0] = (_Float16)a0[0]; o[1] = (_Float16)a0[1];
    o[2] = (_Float16)a1[0]; o[3] = (_Float16)a1[1];
    o[4] = (_Float16)b0[0]; o[5] = (_Float16)b0[1];
    o[6] = (_Float16)b1[0]; o[7] = (_Float16)b1[1];
    return o;
}

// ---- merged: per-block bucket histogram (bid < nBlk) + prep roles --------
//      prep: softmax denom (pbid 0-255), seg_bounds (256), w_prep (257-320).
__global__ __launch_bounds__(256) void prep_hist(
    const int* __restrict__ dst, int* __restrict__ blockBin,
    int* __restrict__ binTotal, int E, int nBlk,
    const float* __restrict__ x, float* __restrict__ sumexp, int n,
    const int* __restrict__ batch, int* __restrict__ lb,
    const float* __restrict__ W2l, const float* __restrict__ W2r,
    const float* __restrict__ W3l, const float* __restrict__ W3r,
    __half* __restrict__ wfrag2, __half* __restrict__ wfrag3)
{
    __shared__ int hist[NBIN];
    __shared__ float wsum[4];
    int t = threadIdx.x;
    int bid = blockIdx.x;
    if (bid < nBlk) {
        for (int i = t; i < NBIN; i += 256) hist[i] = 0;
        __syncthreads();
        int e0 = bid * EPB;
#pragma unroll
        for (int k = 0; k < 32; k++) {
            int e = e0 + (k << 8) + t;
            if (e < E) atomicAdd(&hist[dst[e] >> 8], 1);
        }
        __syncthreads();
        for (int i = t; i < NBIN; i += 256) {
            int c = hist[i];
            blockBin[bid * NBIN + i] = c;
            if (c) atomicAdd(&binTotal[i], c);
        }
        return;
    }
    int pbid = bid - nBlk;
    if (pbid < 256) {
        float s = 0.f;
        int stride = 256 * 256;
        for (int i = pbid * 256 + t; i < n; i += stride)
            s += expf(x[(size_t)i * 6 + 4]);
#pragma unroll
        for (int o = 32; o > 0; o >>= 1) s += __shfl_down(s, o, 64);
        if ((t & 63) == 0) wsum[t >> 6] = s;
        __syncthreads();
        if (t == 0)
            unsafeAtomicAdd(sumexp, wsum[0] + wsum[1] + wsum[2] + wsum[3]);
    } else if (pbid == 256) {
        int b = t;
        if (b > 64) return;
        int lo = 0, hi = n;
        while (lo < hi) {
            int mid = (lo + hi) >> 1;
            if (batch[mid] < b) lo = mid + 1; else hi = mid;
        }
        lb[b] = lo;
    } else {
        bool second = (pbid >= 289);
        int i = (pbid - (second ? 289 : 257)) * 256 + t;
        if (i >= 8192) return;
        int j    = i & 7;
        int m    = (i >> 3) & 15;
        int quad = (i >> 7) & 3;
        int tt   = (i >> 9) & 3;
        int q    = i >> 11;
        int k    = (q & 1) * 32 + quad * 8 + j;
        int col  = tt * 16 + m;
        const float* W = second ? ((q < 2) ? W3l : W3r)
                                : ((q < 2) ? W2l : W2r);
        (second ? wfrag3 : wfrag2)[i] = __float2half_rn(W[k * 64 + col]);
    }
}

// ---- phase B (merged): per-block redundant scan of bin totals + per-bin
//      exclusive scan over block counts. 64 blocks x 512 threads (8 waves).
//      Block 0 publishes binBase[0..NBIN] and rowptr[N]=E.
__global__ __launch_bounds__(512) void blockbin_offs(int* __restrict__ blockBin,
                                                     const int* __restrict__ binTotal,
                                                     int* __restrict__ binBase,
                                                     int* __restrict__ rowptrN,
                                                     int nBlk)
{
    __shared__ int s[NBIN];
    int t = threadIdx.x;
    int tot = binTotal[t];
    s[t] = tot;
    __syncthreads();
    for (int off = 1; off < NBIN; off <<= 1) {
        int v = (t >= off) ? s[t - off] : 0;
        __syncthreads();
        s[t] += v;
        __syncthreads();
    }
    int excl = s[t] - tot;
    if (blockIdx.x == 0) {
        binBase[t] = excl;
        if (t == NBIN - 1) { binBase[NBIN] = s[t]; *rowptrN = s[t]; }
    }
    __syncthreads();

    int wv   = t >> 6;              // 0..7
    int lane = t & 63;
    int bin  = blockIdx.x * 8 + wv;
    int carry = s[bin] - binTotal[bin];   // exclusive base for this bin
    for (int c0 = 0; c0 < nBlk; c0 += 64) {
        int blk = c0 + lane;
        int cnt = (blk < nBlk) ? blockBin[blk * NBIN + bin] : 0;
        int v = cnt;
#pragma unroll
        for (int d = 1; d < 64; d <<= 1) {
            int u = __shfl_up(v, d, 64);
            if (lane >= d) v += u;
        }
        if (blk < nBlk) blockBin[blk * NBIN + bin] = carry + v - cnt;
        carry += __shfl(v, 63, 64);
    }
}

// ---- phase C: place packed (src | local_dst<<24); per-block LDS cursors ---
__global__ __launch_bounds__(256) void bucket_scatter(const int* __restrict__ src,
                                                      const int* __restrict__ dst,
                                                      const int* __restrict__ blockBin,
                                                      int* __restrict__ epck, int E)
{
    __shared__ int cur[NBIN];
    int t = threadIdx.x;
    for (int i = t; i < NBIN; i += 256) cur[i] = blockBin[blockIdx.x * NBIN + i];
    __syncthreads();
    int e0 = blockIdx.x * EPB;
#pragma unroll
    for (int k = 0; k < 32; k++) {
        int e = e0 + (k << 8) + t;
        if (e < E) {
            int d = dst[e];
            int pos = atomicAdd(&cur[d >> 8], 1);
            epck[pos] = src[e] | ((d & 255) << 24);   // src < 2^24
        }
    }
}

// ---- merged phase D + layer 1: per-bucket local CSR, then fused
//      pull-aggregation (6 ch) + matmul for the same 256 nodes. No fences.
__global__ __launch_bounds__(256) void csr_sage1(
    const int* __restrict__ epck, const int* __restrict__ binBase,
    int* __restrict__ rowptr, int* __restrict__ eidx,
    const float* __restrict__ x,
    const float* __restrict__ Wl, const float* __restrict__ bias,
    const float* __restrict__ Wr, __half* __restrict__ out, int N)
{
    __shared__ int cnt[256], s[256], cur[256];
    __shared__ float4 sWl[6 * 16];
    __shared__ float4 sWr[6 * 16];
    int t = threadIdx.x, bkt = blockIdx.x;
    for (int i = t; i < 6 * 16; i += 256) {
        sWl[i] = ((const float4*)Wl)[i];
        sWr[i] = ((const float4*)Wr)[i];
    }
    int base = binBase[bkt], nE = binBase[bkt + 1] - base;
    cnt[t] = 0;
    __syncthreads();
    for (int j = t; j < nE; j += 256)
        atomicAdd(&cnt[(unsigned)epck[base + j] >> 24], 1);
    __syncthreads();
    s[t] = cnt[t];
    __syncthreads();
    for (int off = 1; off < 256; off <<= 1) {
        int v = (t >= off) ? s[t - off] : 0;
        __syncthreads();
        s[t] += v;
        __syncthreads();
    }
    int excl = s[t] - cnt[t];
    cur[t] = excl;
    int node = (bkt << 8) + t;
    if (node < N) rowptr[node] = base + excl;
    __syncthreads();
    for (int j = t; j < nE; j += 256) {
        int v = epck[base + j];
        int pos = atomicAdd(&cur[(unsigned)v >> 24], 1);
        eidx[base + pos] = v & 0xFFFFFF;     // contiguous 16KB span: stays in L2
    }
    __syncthreads();    // eidx writes drained to L2 before re-read

    // ---- sage1 part: this block's nodes == this bucket ----
    if (node >= N) return;
    int eb = base + excl, ee = base + s[t];
    float a[6] = {0.f, 0.f, 0.f, 0.f, 0.f, 0.f};
    for (int j = eb; j < ee; j++) {
        int si = eidx[j];
        const float2* r = (const float2*)(x + (size_t)si * 6);
        float2 r0 = r[0], r1 = r[1], r2 = r[2];
        a[0] += r0.x; a[1] += r0.y; a[2] += r1.x;
        a[3] += r1.y; a[4] += r2.x; a[5] += r2.y;
    }
    float invd = 1.0f / fmaxf((float)(ee - eb), 1.0f);

    const float2* xr2 = (const float2*)(x + (size_t)node * 6);
    float2 x0 = xr2[0], x1 = xr2[1], x2 = xr2[2];
    float hh[6] = {x0.x, x0.y, x1.x, x1.y, x2.x, x2.y};

    float4 acc[16];
#pragma unroll
    for (int cg = 0; cg < 16; cg++) acc[cg] = ((const float4*)bias)[cg];
#pragma unroll
    for (int k = 0; k < 6; k++) {
        float am = a[k] * invd;
        float hk = hh[k];
#pragma unroll
        for (int cg = 0; cg < 16; cg++) {
            float4 wl = sWl[k * 16 + cg];
            float4 wr = sWr[k * 16 + cg];
            acc[cg].x = fmaf(am, wl.x, fmaf(hk, wr.x, acc[cg].x));
            acc[cg].y = fmaf(am, wl.y, fmaf(hk, wr.y, acc[cg].y));
            acc[cg].z = fmaf(am, wl.z, fmaf(hk, wr.z, acc[cg].z));
            acc[cg].w = fmaf(am, wl.w, fmaf(hk, wr.w, acc[cg].w));
        }
    }
    __half* orow = out + (size_t)node * 64;
#pragma unroll
    for (int cg = 0; cg < 8; cg++) {
        float4 a0 = acc[2 * cg], a1 = acc[2 * cg + 1];
        float4 o;
        ((__half2*)&o)[0] = __floats2half2_rn(a0.x, a0.y);
        ((__half2*)&o)[1] = __floats2half2_rn(a0.z, a0.w);
        ((__half2*)&o)[2] = __floats2half2_rn(a1.x, a1.y);
        ((__half2*)&o)[3] = __floats2half2_rn(a1.z, a1.w);
        ((float4*)orow)[cg] = o;
    }
}

// ---- BN stats (separate pass — layer 1 only). fp16 input, 8 ch/thr ------
__global__ __launch_bounds__(256) void bn_stats(const __half* __restrict__ h,
                                                float* __restrict__ stats, size_t nchunk)
{
    __shared__ float ls[64], lss[64];
    int t = threadIdx.x;
    if (t < 64) { ls[t] = 0.f; lss[t] = 0.f; }
    __syncthreads();
    float s[8]  = {0.f, 0.f, 0.f, 0.f, 0.f, 0.f, 0.f, 0.f};
    float ss[8] = {0.f, 0.f, 0.f, 0.f, 0.f, 0.f, 0.f, 0.f};
    size_t stride = (size_t)gridDim.x * 256;
    for (size_t i = (size_t)blockIdx.x * 256 + t; i < nchunk; i += stride) {
        float4 hv = ((const float4*)h)[i];
        const __half2* hp = (const __half2*)&hv;
#pragma unroll
        for (int j = 0; j < 4; j++) {
            float2 f = __half22float2(hp[j]);
            s[2 * j]     += f.x;
            ss[2 * j]     = fmaf(f.x, f.x, ss[2 * j]);
            s[2 * j + 1] += f.y;
            ss[2 * j + 1] = fmaf(f.y, f.y, ss[2 * j + 1]);
        }
    }
    int c0 = (t & 7) * 8;     // chunk stride is a multiple of 8 chunks
#pragma unroll
    for (int j = 0; j < 8; j++) {
        atomicAdd(&ls[c0 + j], s[j]);
        atomicAdd(&lss[c0 + j], ss[j]);
    }
    __syncthreads();
    if (t < 64) {
        unsafeAtomicAdd(&stats[t], ls[t]);
        unsafeAtomicAdd(&stats[64 + t], lss[t]);
    }
}

// ---- bn_dual: v = relu(bn(h)); h8 = fp8(v) only (R26: h16 stream gone). --
__global__ __launch_bounds__(256) void bn_dual(const __half* __restrict__ h,
                                               const float* __restrict__ stats,
                                               const float* __restrict__ g,
                                               const float* __restrict__ be,
                                               unsigned* __restrict__ h8,
                                               float invN, size_t nchunk)
{
    __shared__ float ssc[64], ssh[64];
    int t = threadIdx.x;
    if (t < 64) {
        float mu  = stats[t] * invN;
        float var = stats[64 + t] * invN - mu * mu;
        float sc  = g[t] / sqrtf(var + EPS_BN);
        ssc[t] = sc;
        ssh[t] = fmaf(-mu, sc, be[t]);
    }
    __syncthreads();
    size_t i8 = (size_t)blockIdx.x * 256 + t;
    if (i8 >= nchunk) return;
    int c0 = (int)((i8 * 8) & 63);
    float4 hv = ((const float4*)h)[i8];
    const __half2* hp = (const __half2*)&hv;
    float v[8];
#pragma unroll
    for (int j = 0; j < 4; j++) {
        float2 f = __half22float2(hp[j]);
        v[2 * j] = f.x;
        v[2 * j + 1] = f.y;
    }
#pragma unroll
    for (int j = 0; j < 8; j++) {
        int c = c0 + j;
        v[j] = fmaxf(fmaf(v[j], ssc[c], ssh[c]), 0.f);
    }
    int p0 = __builtin_amdgcn_cvt_pk_fp8_f32(v[0], v[1], 0, false);
    p0     = __builtin_amdgcn_cvt_pk_fp8_f32(v[2], v[3], p0, true);
    int p1 = __builtin_amdgcn_cvt_pk_fp8_f32(v[4], v[5], 0, false);
    p1     = __builtin_amdgcn_cvt_pk_fp8_f32(v[6], v[7], p1, true);
    uint2 pk;
    pk.x = (unsigned)p0;
    pk.y = (unsigned)p1;
    ((uint2*)h8)[i8] = pk;
}

// ---- fused aggregation + MFMA GEMM + BN stats. Self-term from h8 (R26). --
#define TSTRIDE 72
__global__ __launch_bounds__(256) void agg_mm_mfma(
    const int* __restrict__ rowptr, const int* __restrict__ eidx,
    const unsigned* __restrict__ h8,
    const __half* __restrict__ wfh, const float* __restrict__ bias,
    __half* __restrict__ out, float* __restrict__ statsTmp, int n)
{
    __shared__ float ls[64], lss[64];
    __shared__ _Float16 sT[4][16 * TSTRIDE];   // 4 waves x 16 nodes x 64ch
    int t = threadIdx.x;
    if (t < 64) { ls[t] = 0.f; lss[t] = 0.f; }

    int wv = t >> 6, lane = t & 63;
    int node0 = (blockIdx.x * 4 + wv) * 16;

    // ---- gather phase ----
    int grp = lane >> 4, cq = lane & 15;
#pragma unroll 1
    for (int r = 0; r < 4; r++) {
        int node = node0 + r * 4 + grp;
        int b = 0, e = 0;
        if (node < n) { b = rowptr[node]; e = rowptr[node + 1]; }

        float4 a0 = {0,0,0,0}, a1 = {0,0,0,0}, a2 = {0,0,0,0}, a3 = {0,0,0,0};
#define EDGE(S, ACC)                                                            \
        {                                                                       \
            unsigned r_ = h8[(size_t)(S) * 16 + cq];                            \
            f32x2 lo_ = __builtin_amdgcn_cvt_pk_f32_fp8(r_, false);             \
            f32x2 hi_ = __builtin_amdgcn_cvt_pk_f32_fp8(r_, true);              \
            ACC.x += lo_[0]; ACC.y += lo_[1]; ACC.z += hi_[0]; ACC.w += hi_[1]; \
        }
        int j = b;
        for (; j + 4 <= e; j += 4) {
            int s0 = eidx[j], s1 = eidx[j + 1], s2 = eidx[j + 2], s3 = eidx[j + 3];
            EDGE(s0, a0) EDGE(s1, a1) EDGE(s2, a2) EDGE(s3, a3)
        }
        for (; j < e; j++) {
            int s = eidx[j];
            EDGE(s, a0)
        }
#undef EDGE
        float ax = a0.x + a1.x + a2.x + a3.x;
        float ay = a0.y + a1.y + a2.y + a3.y;
        float az = a0.z + a1.z + a2.z + a3.z;
        float aw = a0.w + a1.w + a2.w + a3.w;
        float invd = 1.0f / fmaxf((float)(e - b), 1.0f);
        __half2 o01 = __floats2half2_rn(ax * invd, ay * invd);
        __half2 o23 = __floats2half2_rn(az * invd, aw * invd);
        float2 ov;
        ((__half2*)&ov)[0] = o01;
        ((__half2*)&ov)[1] = o23;
        *(float2*)(&sT[wv][(r * 4 + grp) * TSTRIDE + cq * 4]) = ov;
    }
    __syncthreads();    // drains LDS writes (also covers ls/lss init)

    // ---- GEMM phase ----
    int m = lane & 15, quad = lane >> 4;
    if (node0 < n) {
        const f16x8* wf = (const f16x8*)wfh;   // frag idx ((q*4+tt)*4+quad)*16+m

        int nodeA = node0 + m;
        if (nodeA >= n) nodeA = n - 1;         // tail-safe global loads

        const uint2* hrow8 = (const uint2*)(h8 + (size_t)nodeA * 16);
        uint2 rlo = hrow8[quad];               // channels quad*8 .. +7
        uint2 rhi = hrow8[4 + quad];           // channels 32+quad*8 .. +7
        f16x8 af[4];
        af[0] = *(const f16x8*)(&sT[wv][m * TSTRIDE + quad * 8]);
        af[1] = *(const f16x8*)(&sT[wv][m * TSTRIDE + 32 + quad * 8]);
        af[2] = fp8x8_to_h8(rlo);
        af[3] = fp8x8_to_h8(rhi);

#pragma unroll
        for (int tt = 0; tt < 4; tt++) {
            float bv = bias[tt * 16 + m];
            f32x4 c = {bv, bv, bv, bv};
#pragma unroll
            for (int q = 0; q < 4; q++)
                c = __builtin_amdgcn_mfma_f32_16x16x32_f16(
                        af[q], wf[((q * 4 + tt) * 4 + quad) * 16 + m], c, 0, 0, 0);
            float s = 0.f, ss = 0.f;
#pragma unroll
            for (int r = 0; r < 4; r++) {
                int row = node0 + quad * 4 + r;
                float v = (row < n) ? c[r] : 0.f;
                if (row < n) out[(size_t)row * 64 + tt * 16 + m] = __float2half_rn(v);
                s += v;
                ss = fmaf(v, v, ss);
            }
            s  += __shfl_xor(s, 16, 64);  s  += __shfl_xor(s, 32, 64);
            ss += __shfl_xor(ss, 16, 64); ss += __shfl_xor(ss, 32, 64);
            if (quad == 0) {
                atomicAdd(&ls[tt * 16 + m], s);
                atomicAdd(&lss[tt * 16 + m], ss);
            }
        }
    }
    __syncthreads();
    if (t < 64) {
        float* slot = statsTmp + (size_t)(blockIdx.x & 63) * 128;
        unsafeAtomicAdd(&slot[t], ls[t]);
        unsafeAtomicAdd(&slot[64 + t], lss[t]);
    }
}

// ---- stats_reduce: fold 64 scratch slots into stats[128] ------------------
__global__ __launch_bounds__(128) void stats_reduce(const float* __restrict__ tmp,
                                                    float* __restrict__ stats)
{
    int t = threadIdx.x;       // 0..127
    float s = 0.f;
#pragma unroll 8
    for (int k = 0; k < 64; k++) s += tmp[k * 128 + t];
    stats[t] = s;
}

// ---- fused layer-3 BN+ReLU + attention-weighted segment pooling ----------
__global__ __launch_bounds__(256) void bn_pool(
    const __half* __restrict__ h, const float* __restrict__ stats,
    const float* __restrict__ g, const float* __restrict__ be,
    const float* __restrict__ x, const int* __restrict__ batch,
    float* __restrict__ rawpool, float invN, int N, int chunk)
{
    int wid  = blockIdx.x * 4 + (threadIdx.x >> 6);
    int lane = threadIdx.x & 63;
    int i0 = wid * chunk;
    if (i0 >= N) return;
    int i1 = min(i0 + chunk, N);

    float mu  = stats[lane] * invN;
    float var = stats[64 + lane] * invN - mu * mu;
    float sc  = g[lane] / sqrtf(var + EPS_BN);
    float sh  = fmaf(-mu, sc, be[lane]);

    int   cur = batch[i0];
    float acc = 0.f;
    for (int i = i0; i < i1; i++) {
        int bi = batch[i];
        if (bi != cur) {
            unsafeAtomicAdd(&rawpool[cur * 64 + lane], acc);
            acc = 0.f;
            cur = bi;
        }
        float w = expf(x[(size_t)i * 6 + 4]);
        float v = fmaxf(fmaf(__half2float(h[(size_t)i * 64 + lane]), sc, sh), 0.f);
        acc = fmaf(v, w, acc);
    }
    unsafeAtomicAdd(&rawpool[cur * 64 + lane], acc);
}

// ---- heads: normalize rawpool by 1/sumexp and counts, then 2 tiny MLPs ----
__global__ __launch_bounds__(64) void heads_kernel(
    const float* __restrict__ rawpool, const float* __restrict__ sumexp,
    const int* __restrict__ lb,
    const float* __restrict__ phW1, const float* __restrict__ phb1,
    const float* __restrict__ phW2, const float* __restrict__ phb2,
    const float* __restrict__ trW1, const float* __restrict__ trb1,
    const float* __restrict__ trW2, const float* __restrict__ trb2,
    float* __restrict__ out)
{
    int b = blockIdx.x, t = threadIdx.x;
    __shared__ float p[64], h1[32], h2[16];
    float cnt = (float)(lb[b + 1] - lb[b]);
    p[t] = rawpool[b * 64 + t] / (sumexp[0] * fmaxf(cnt, 1.0f));
    __syncthreads();
    if (t < 32) {
        float s = phb1[t];
        for (int k = 0; k < 64; k++) s = fmaf(p[k], phW1[k * 32 + t], s);
        h1[t] = fmaxf(s, 0.f);
    } else if (t < 48) {
        int tt = t - 32;
        float s = trb1[tt];
        for (int k = 0; k < 64; k++) s = fmaf(p[k], trW1[k * 16 + tt], s);
        h2[tt] = fmaxf(s, 0.f);
    }
    __syncthreads();
    if (t < 3) {
        float s = phb2[t];
        for (int k = 0; k < 32; k++) s = fmaf(h1[k], phW2[k * 3 + t], s);
        out[b * 3 + t] = s;
    } else if (t == 63) {
        float s = trb2[0];
        for (int k = 0; k < 16; k++) s = fmaf(h2[k], trW2[k], s);
        out[192 + b] = 1.0f / (1.0f + expf(-s));
    }
}

extern "C" void kernel_launch(void* const* d_in, const int* in_sizes, int n_in,
                              void* d_out, int out_size, void* d_ws, size_t ws_size,
                              hipStream_t stream)
{
    const float* x     = (const float*)d_in[0];
    const int*   ei    = (const int*)d_in[1];
    const int*   batch = (const int*)d_in[2];
    const float* W1l = (const float*)d_in[3];
    const float* b1  = (const float*)d_in[4];
    const float* W1r = (const float*)d_in[5];
    const float* W2l = (const float*)d_in[6];
    const float* b2  = (const float*)d_in[7];
    const float* W2r = (const float*)d_in[8];
    const float* W3l = (const float*)d_in[9];
    const float* b3  = (const float*)d_in[10];
    const float* W3r = (const float*)d_in[11];
    const float* g1  = (const float*)d_in[12];
    const float* be1 = (const float*)d_in[13];
    const float* g2  = (const float*)d_in[14];
    const float* be2 = (const float*)d_in[15];
    const float* g3  = (const float*)d_in[16];
    const float* be3 = (const float*)d_in[17];
    const float* phW1 = (const float*)d_in[18];
    const float* phb1 = (const float*)d_in[19];
    const float* phW2 = (const float*)d_in[20];
    const float* phb2 = (const float*)d_in[21];
    const float* trW1 = (const float*)d_in[22];
    const float* trb1 = (const float*)d_in[23];
    const float* trW2 = (const float*)d_in[24];
    const float* trb2 = (const float*)d_in[25];

    const int N = in_sizes[0] / 6;
    const int E = in_sizes[1] / 2;
    const int* src = ei;
    const int* dst = ei + E;

    const int NB    = (N + 255) >> 8;          // 391 buckets
    const int nBlkA = (E + EPB - 1) / EPB;     // 196 partition blocks

    float* ws = (float*)d_ws;
    const size_t N64 = (size_t)N * 64;
    float*  hA      = ws;                          // N*64 region (fp16 raw h1/h3)
    float*  hB      = ws + N64;                    // N*64 region (fp16 raw h2)
    // (h16 region retired in R26 — layout offsets kept)
    int*   epck     = (int*)(ws + 3 * N64);        // E packed src|dl<<24
    int*   eidx     = epck + E;                    // E (CSR by dst)
    int*   blockBin = eidx + E;                    // nBlkA * NBIN
    // --- contiguous zero region: binTotal + stats + statsTmp + rawpool + sumexp
    int*   binTotal = blockBin + (size_t)nBlkA * NBIN;   // NBIN
    float* stats    = (float*)(binTotal + NBIN);   // 3 * 128
    float* statsTmp = stats + 384;                 // 2 * 64 * 128
    float* rawpool  = statsTmp + 16384;            // 64*64
    float* sumexp   = rawpool + 4096;              // 1 (pad 4)
    // --- end zero region ---
    int*   binBase  = (int*)(sumexp + 4);          // NBIN + 1
    int*   rowptr   = binBase + NBIN + 1;          // N + 1
    int*   lb       = rowptr + N + 1;              // 65 (pad 72)
    __half* wfrag2  = (__half*)(lb + 72);          // 8192 fp16
    __half* wfrag3  = wfrag2 + 8192;               // 8192 fp16
    unsigned* h8    = (unsigned*)(wfrag3 + 8192);  // N*16 dwords (fp8 rows)
    float* out      = (float*)d_out;

    const int mfmaBlocks = (N + 63) / 64;          // 1563 (4 x 16-node tiles/block)
    const size_t nchunk  = N64 / 8;                // 8-half chunks (N64 % 8 == 0)
    const int cvt8Blocks = (int)((nchunk + 255) / 256);
    const int PBLK = 1024;                         // bn_pool blocks (4 waves each)
    const int chunk = (N + PBLK * 4 - 1) / (PBLK * 4);
    const float invN = 1.0f / (float)N;

    // ---- zero accumulators; merged prep+hist ----
    size_t zbytes = (char*)(sumexp + 4) - (char*)binTotal;
    hipMemsetAsync(binTotal, 0, zbytes, stream);
    prep_hist<<<nBlkA + 321, 256, 0, stream>>>(dst, blockBin, binTotal, E, nBlkA,
                                               x, sumexp, N, batch, lb,
                                               W2l, W2r, W3l, W3r, wfrag2, wfrag3);

    // ---- CSR build (scan merged into blockbin_offs) ----
    blockbin_offs<<<NBIN / 8, 512, 0, stream>>>(blockBin, binTotal, binBase,
                                                rowptr + N, nBlkA);
    bucket_scatter<<<nBlkA, 256, 0, stream>>>(src, dst, blockBin, epck, E);

    // ---- merged CSR-local + layer 1 ----
    csr_sage1<<<NB, 256, 0, stream>>>(epck, binBase, rowptr, eidx,
                                      x, W1l, b1, W1r, (__half*)hA, N);
    bn_stats<<<1024, 256, 0, stream>>>((const __half*)hA, stats, nchunk);
    bn_dual<<<cvt8Blocks, 256, 0, stream>>>((const __half*)hA, stats, g1, be1,
                                            h8, invN, nchunk);

    // ---- layer 2 (fused gather+GEMM -> hB; stats2 -> 64-slot scratch) ----
    agg_mm_mfma<<<mfmaBlocks, 256, 0, stream>>>(rowptr, eidx, h8, wfrag2, b2,
                                                (__half*)hB, statsTmp, N);
    stats_reduce<<<1, 128, 0, stream>>>(statsTmp, stats + 128);
    bn_dual<<<cvt8Blocks, 256, 0, stream>>>((const __half*)hB, stats + 128, g2, be2,
                                            h8, invN, nchunk);

    // ---- layer 3 (fused gather+GEMM -> hA; stats3 -> 64-slot scratch) ----
    agg_mm_mfma<<<mfmaBlocks, 256, 0, stream>>>(rowptr, eidx, h8, wfrag3, b3,
                                                (__half*)hA, statsTmp + 8192, N);
    stats_reduce<<<1, 128, 0, stream>>>(statsTmp + 8192, stats + 256);

    // ---- fused BN3 + attention pooling + heads ----
    bn_pool<<<PBLK, 256, 0, stream>>>((const __half*)hA, stats + 256, g3, be3,
                                      x, batch, rawpool, invN, N, chunk);
    heads_kernel<<<64, 64, 0, stream>>>(rawpool, sumexp, lb,
                                        phW1, phb1, phW2, phb2,
                                        trW1, trb1, trW2, trb2, out);
}

// Round 7
// 329.016 us; speedup vs baseline: 1.0867x; 1.0304x over previous
//
#include <hip/hip_runtime.h>
#include <hip/hip_fp16.h>
#include <cstdint>
#include <cstddef>

// ---------------------------------------------------------------------------
// TopoGNN: 3x SAGEConv(mean) + BN + ReLU, softmax-attention pooling, 2 heads.
// N=100000 nodes, E=1600000 edges, B=64 segments, IN_CH=6, HID=64.
// R5 (754us) bucket-CSR. R12 (474us) MFMA GEMM. R17/R19 (381us) fp8 gather.
// R20 (373us) agg fused into MFMA. R21 (361us) merges. R22 (357us) h fp16.
// R23 (766us REGR): per-block __threadfence evicts L2. Never fence gathers.
// R24 (341us): fence-free merges (prep+hist, csr+sage1).
// R25 (357us REGR): stats-prologue broadcast folds cost +18us. Keep the
//     1-block stats_reduce dispatch instead.
// R26 (339us): h16-elim — GEMM self-term decoded from h8.
// R27: BN-on-the-fly. Raw h stored fp8 (pre-BN; one quant/layer as before).
//     agg gather decodes fp8 and applies relu(sc*v+sh) in f32 during
//     accumulation (BN consts via 64-thr LDS prologue from final stats).
//     Self-term BN'd in-register. Epilogue writes fp8 bytes. bn_dual x2
//     DELETED (their 38MB round-trip + 2 launches). csr_sage1 writes fp8
//     packed; bn_stats/bn_pool read fp8. 12 dispatches.
// ---------------------------------------------------------------------------

#define EPB 8192   // edges per partition block (256 thr x 32)
#define NBIN 512   // padded bucket count (actual NB = ceil(N/256) <= 512)
#define EPS_BN 1e-5f

typedef _Float16 f16x8 __attribute__((ext_vector_type(8)));
typedef float    f32x4 __attribute__((ext_vector_type(4)));
typedef float    f32x2 __attribute__((ext_vector_type(2)));

// ---- merged: per-block bucket histogram (bid < nBlk) + prep roles --------
__global__ __launch_bounds__(256) void prep_hist(
    const int* __restrict__ dst, int* __restrict__ blockBin,
    int* __restrict__ binTotal, int E, int nBlk,
    const float* __restrict__ x, float* __restrict__ sumexp, int n,
    const int* __restrict__ batch, int* __restrict__ lb,
    const float* __restrict__ W2l, const float* __restrict__ W2r,
    const float* __restrict__ W3l, const float* __restrict__ W3r,
    __half* __restrict__ wfrag2, __half* __restrict__ wfrag3)
{
    __shared__ int hist[NBIN];
    __shared__ float wsum[4];
    int t = threadIdx.x;
    int bid = blockIdx.x;
    if (bid < nBlk) {
        for (int i = t; i < NBIN; i += 256) hist[i] = 0;
        __syncthreads();
        int e0 = bid * EPB;
#pragma unroll
        for (int k = 0; k < 32; k++) {
            int e = e0 + (k << 8) + t;
            if (e < E) atomicAdd(&hist[dst[e] >> 8], 1);
        }
        __syncthreads();
        for (int i = t; i < NBIN; i += 256) {
            int c = hist[i];
            blockBin[bid * NBIN + i] = c;
            if (c) atomicAdd(&binTotal[i], c);
        }
        return;
    }
    int pbid = bid - nBlk;
    if (pbid < 256) {
        float s = 0.f;
        int stride = 256 * 256;
        for (int i = pbid * 256 + t; i < n; i += stride)
            s += expf(x[(size_t)i * 6 + 4]);
#pragma unroll
        for (int o = 32; o > 0; o >>= 1) s += __shfl_down(s, o, 64);
        if ((t & 63) == 0) wsum[t >> 6] = s;
        __syncthreads();
        if (t == 0)
            unsafeAtomicAdd(sumexp, wsum[0] + wsum[1] + wsum[2] + wsum[3]);
    } else if (pbid == 256) {
        int b = t;
        if (b > 64) return;
        int lo = 0, hi = n;
        while (lo < hi) {
            int mid = (lo + hi) >> 1;
            if (batch[mid] < b) lo = mid + 1; else hi = mid;
        }
        lb[b] = lo;
    } else {
        bool second = (pbid >= 289);
        int i = (pbid - (second ? 289 : 257)) * 256 + t;
        if (i >= 8192) return;
        int j    = i & 7;
        int m    = (i >> 3) & 15;
        int quad = (i >> 7) & 3;
        int tt   = (i >> 9) & 3;
        int q    = i >> 11;
        int k    = (q & 1) * 32 + quad * 8 + j;
        int col  = tt * 16 + m;
        const float* W = second ? ((q < 2) ? W3l : W3r)
                                : ((q < 2) ? W2l : W2r);
        (second ? wfrag3 : wfrag2)[i] = __float2half_rn(W[k * 64 + col]);
    }
}

// ---- phase B: scan of bin totals + per-bin exclusive block-count scan ----
__global__ __launch_bounds__(512) void blockbin_offs(int* __restrict__ blockBin,
                                                     const int* __restrict__ binTotal,
                                                     int* __restrict__ binBase,
                                                     int* __restrict__ rowptrN,
                                                     int nBlk)
{
    __shared__ int s[NBIN];
    int t = threadIdx.x;
    int tot = binTotal[t];
    s[t] = tot;
    __syncthreads();
    for (int off = 1; off < NBIN; off <<= 1) {
        int v = (t >= off) ? s[t - off] : 0;
        __syncthreads();
        s[t] += v;
        __syncthreads();
    }
    int excl = s[t] - tot;
    if (blockIdx.x == 0) {
        binBase[t] = excl;
        if (t == NBIN - 1) { binBase[NBIN] = s[t]; *rowptrN = s[t]; }
    }
    __syncthreads();

    int wv   = t >> 6;              // 0..7
    int lane = t & 63;
    int bin  = blockIdx.x * 8 + wv;
    int carry = s[bin] - binTotal[bin];   // exclusive base for this bin
    for (int c0 = 0; c0 < nBlk; c0 += 64) {
        int blk = c0 + lane;
        int cnt = (blk < nBlk) ? blockBin[blk * NBIN + bin] : 0;
        int v = cnt;
#pragma unroll
        for (int d = 1; d < 64; d <<= 1) {
            int u = __shfl_up(v, d, 64);
            if (lane >= d) v += u;
        }
        if (blk < nBlk) blockBin[blk * NBIN + bin] = carry + v - cnt;
        carry += __shfl(v, 63, 64);
    }
}

// ---- phase C: place packed (src | local_dst<<24); per-block LDS cursors ---
__global__ __launch_bounds__(256) void bucket_scatter(const int* __restrict__ src,
                                                      const int* __restrict__ dst,
                                                      const int* __restrict__ blockBin,
                                                      int* __restrict__ epck, int E)
{
    __shared__ int cur[NBIN];
    int t = threadIdx.x;
    for (int i = t; i < NBIN; i += 256) cur[i] = blockBin[blockIdx.x * NBIN + i];
    __syncthreads();
    int e0 = blockIdx.x * EPB;
#pragma unroll
    for (int k = 0; k < 32; k++) {
        int e = e0 + (k << 8) + t;
        if (e < E) {
            int d = dst[e];
            int pos = atomicAdd(&cur[d >> 8], 1);
            epck[pos] = src[e] | ((d & 255) << 24);   // src < 2^24
        }
    }
}

// ---- merged phase D + layer 1: per-bucket local CSR + sage1 (fp8 out) ----
__global__ __launch_bounds__(256) void csr_sage1(
    const int* __restrict__ epck, const int* __restrict__ binBase,
    int* __restrict__ rowptr, int* __restrict__ eidx,
    const float* __restrict__ x,
    const float* __restrict__ Wl, const float* __restrict__ bias,
    const float* __restrict__ Wr, unsigned* __restrict__ out, int N)
{
    __shared__ int cnt[256], s[256], cur[256];
    __shared__ float4 sWl[6 * 16];
    __shared__ float4 sWr[6 * 16];
    int t = threadIdx.x, bkt = blockIdx.x;
    for (int i = t; i < 6 * 16; i += 256) {
        sWl[i] = ((const float4*)Wl)[i];
        sWr[i] = ((const float4*)Wr)[i];
    }
    int base = binBase[bkt], nE = binBase[bkt + 1] - base;
    cnt[t] = 0;
    __syncthreads();
    for (int j = t; j < nE; j += 256)
        atomicAdd(&cnt[(unsigned)epck[base + j] >> 24], 1);
    __syncthreads();
    s[t] = cnt[t];
    __syncthreads();
    for (int off = 1; off < 256; off <<= 1) {
        int v = (t >= off) ? s[t - off] : 0;
        __syncthreads();
        s[t] += v;
        __syncthreads();
    }
    int excl = s[t] - cnt[t];
    cur[t] = excl;
    int node = (bkt << 8) + t;
    if (node < N) rowptr[node] = base + excl;
    __syncthreads();
    for (int j = t; j < nE; j += 256) {
        int v = epck[base + j];
        int pos = atomicAdd(&cur[(unsigned)v >> 24], 1);
        eidx[base + pos] = v & 0xFFFFFF;     // contiguous 16KB span: stays in L2
    }
    __syncthreads();    // eidx writes drained to L2 before re-read

    // ---- sage1 part: this block's nodes == this bucket ----
    if (node >= N) return;
    int eb = base + excl, ee = base + s[t];
    float a[6] = {0.f, 0.f, 0.f, 0.f, 0.f, 0.f};
    for (int j = eb; j < ee; j++) {
        int si = eidx[j];
        const float2* r = (const float2*)(x + (size_t)si * 6);
        float2 r0 = r[0], r1 = r[1], r2 = r[2];
        a[0] += r0.x; a[1] += r0.y; a[2] += r1.x;
        a[3] += r1.y; a[4] += r2.x; a[5] += r2.y;
    }
    float invd = 1.0f / fmaxf((float)(ee - eb), 1.0f);

    const float2* xr2 = (const float2*)(x + (size_t)node * 6);
    float2 x0 = xr2[0], x1 = xr2[1], x2 = xr2[2];
    float hh[6] = {x0.x, x0.y, x1.x, x1.y, x2.x, x2.y};

    float4 acc[16];
#pragma unroll
    for (int cg = 0; cg < 16; cg++) acc[cg] = ((const float4*)bias)[cg];
#pragma unroll
    for (int k = 0; k < 6; k++) {
        float am = a[k] * invd;
        float hk = hh[k];
#pragma unroll
        for (int cg = 0; cg < 16; cg++) {
            float4 wl = sWl[k * 16 + cg];
            float4 wr = sWr[k * 16 + cg];
            acc[cg].x = fmaf(am, wl.x, fmaf(hk, wr.x, acc[cg].x));
            acc[cg].y = fmaf(am, wl.y, fmaf(hk, wr.y, acc[cg].y));
            acc[cg].z = fmaf(am, wl.z, fmaf(hk, wr.z, acc[cg].z));
            acc[cg].w = fmaf(am, wl.w, fmaf(hk, wr.w, acc[cg].w));
        }
    }
    // raw h1 -> fp8 row (16 dwords)
    unsigned px[16];
#pragma unroll
    for (int cg = 0; cg < 16; cg++) {
        float4 av = acc[cg];
        int p = __builtin_amdgcn_cvt_pk_fp8_f32(av.x, av.y, 0, false);
        p     = __builtin_amdgcn_cvt_pk_fp8_f32(av.z, av.w, p, true);
        px[cg] = (unsigned)p;
    }
    uint4* orow = (uint4*)(out + (size_t)node * 16);
    orow[0] = make_uint4(px[0],  px[1],  px[2],  px[3]);
    orow[1] = make_uint4(px[4],  px[5],  px[6],  px[7]);
    orow[2] = make_uint4(px[8],  px[9],  px[10], px[11]);
    orow[3] = make_uint4(px[12], px[13], px[14], px[15]);
}

// ---- BN stats (layer 1 only). fp8 raw input, 8 ch (one uint2) per iter ---
__global__ __launch_bounds__(256) void bn_stats(const uint2* __restrict__ h8,
                                                float* __restrict__ stats, size_t npair)
{
    __shared__ float ls[64], lss[64];
    int t = threadIdx.x;
    if (t < 64) { ls[t] = 0.f; lss[t] = 0.f; }
    __syncthreads();
    float s[8]  = {0.f, 0.f, 0.f, 0.f, 0.f, 0.f, 0.f, 0.f};
    float ss[8] = {0.f, 0.f, 0.f, 0.f, 0.f, 0.f, 0.f, 0.f};
    size_t stride = (size_t)gridDim.x * 256;
    for (size_t i = (size_t)blockIdx.x * 256 + t; i < npair; i += stride) {
        uint2 r = h8[i];
        f32x2 q0 = __builtin_amdgcn_cvt_pk_f32_fp8(r.x, false);
        f32x2 q1 = __builtin_amdgcn_cvt_pk_f32_fp8(r.x, true);
        f32x2 q2 = __builtin_amdgcn_cvt_pk_f32_fp8(r.y, false);
        f32x2 q3 = __builtin_amdgcn_cvt_pk_f32_fp8(r.y, true);
        s[0] += q0[0]; ss[0] = fmaf(q0[0], q0[0], ss[0]);
        s[1] += q0[1]; ss[1] = fmaf(q0[1], q0[1], ss[1]);
        s[2] += q1[0]; ss[2] = fmaf(q1[0], q1[0], ss[2]);
        s[3] += q1[1]; ss[3] = fmaf(q1[1], q1[1], ss[3]);
        s[4] += q2[0]; ss[4] = fmaf(q2[0], q2[0], ss[4]);
        s[5] += q2[1]; ss[5] = fmaf(q2[1], q2[1], ss[5]);
        s[6] += q3[0]; ss[6] = fmaf(q3[0], q3[0], ss[6]);
        s[7] += q3[1]; ss[7] = fmaf(q3[1], q3[1], ss[7]);
    }
    int c0 = (t & 7) * 8;     // stride is a multiple of 8 pairs
#pragma unroll
    for (int j = 0; j < 8; j++) {
        atomicAdd(&ls[c0 + j], s[j]);
        atomicAdd(&lss[c0 + j], ss[j]);
    }
    __syncthreads();
    if (t < 64) {
        unsafeAtomicAdd(&stats[t], ls[t]);
        unsafeAtomicAdd(&stats[64 + t], lss[t]);
    }
}

// ---- fused BN-on-the-fly aggregation + MFMA GEMM + BN stats (R27) --------
//      hr_in: raw fp8 rows of PREVIOUS layer; BN(stats,g,be) applied in f32
//      during gather & self-term. hr_out: raw fp8 rows of THIS layer.
#define TSTRIDE 72
__global__ __launch_bounds__(256) void agg_mm_mfma(
    const int* __restrict__ rowptr, const int* __restrict__ eidx,
    const unsigned* __restrict__ hr_in,
    const float* __restrict__ stats, const float* __restrict__ g,
    const float* __restrict__ be,
    const __half* __restrict__ wfh, const float* __restrict__ bias,
    unsigned char* __restrict__ hr_out, float* __restrict__ statsTmp,
    float invN, int n)
{
    __shared__ float ls[64], lss[64];
    __shared__ float ssc[64], ssh[64];
    __shared__ _Float16 sT[4][16 * TSTRIDE];   // 4 waves x 16 nodes x 64ch
    int t = threadIdx.x;
    if (t < 64) {
        ls[t] = 0.f; lss[t] = 0.f;
        float mu  = stats[t] * invN;
        float var = stats[64 + t] * invN - mu * mu;
        float sc  = g[t] / sqrtf(var + EPS_BN);
        ssc[t] = sc;
        ssh[t] = fmaf(-mu, sc, be[t]);
    }
    __syncthreads();   // ssc/ssh visible to all waves

    int wv = t >> 6, lane = t & 63;
    int node0 = (blockIdx.x * 4 + wv) * 16;

    // ---- gather phase (BN+relu applied per decoded value) ----
    int grp = lane >> 4, cq = lane & 15;
    float sc0 = ssc[4 * cq],     sh0 = ssh[4 * cq];
    float sc1 = ssc[4 * cq + 1], sh1 = ssh[4 * cq + 1];
    float sc2 = ssc[4 * cq + 2], sh2 = ssh[4 * cq + 2];
    float sc3 = ssc[4 * cq + 3], sh3 = ssh[4 * cq + 3];
#pragma unroll 1
    for (int r = 0; r < 4; r++) {
        int node = node0 + r * 4 + grp;
        int b = 0, e = 0;
        if (node < n) { b = rowptr[node]; e = rowptr[node + 1]; }

        float4 a0 = {0,0,0,0}, a1 = {0,0,0,0}, a2 = {0,0,0,0}, a3 = {0,0,0,0};
#define EDGE(S, ACC)                                                            \
        {                                                                       \
            unsigned r_ = hr_in[(size_t)(S) * 16 + cq];                         \
            f32x2 lo_ = __builtin_amdgcn_cvt_pk_f32_fp8(r_, false);             \
            f32x2 hi_ = __builtin_amdgcn_cvt_pk_f32_fp8(r_, true);              \
            ACC.x += fmaxf(fmaf(lo_[0], sc0, sh0), 0.f);                        \
            ACC.y += fmaxf(fmaf(lo_[1], sc1, sh1), 0.f);                        \
            ACC.z += fmaxf(fmaf(hi_[0], sc2, sh2), 0.f);                        \
            ACC.w += fmaxf(fmaf(hi_[1], sc3, sh3), 0.f);                        \
        }
        int j = b;
        for (; j + 4 <= e; j += 4) {
            int s0 = eidx[j], s1 = eidx[j + 1], s2 = eidx[j + 2], s3 = eidx[j + 3];
            EDGE(s0, a0) EDGE(s1, a1) EDGE(s2, a2) EDGE(s3, a3)
        }
        for (; j < e; j++) {
            int s = eidx[j];
            EDGE(s, a0)
        }
#undef EDGE
        float ax = a0.x + a1.x + a2.x + a3.x;
        float ay = a0.y + a1.y + a2.y + a3.y;
        float az = a0.z + a1.z + a2.z + a3.z;
        float aw = a0.w + a1.w + a2.w + a3.w;
        float invd = 1.0f / fmaxf((float)(e - b), 1.0f);
        __half2 o01 = __floats2half2_rn(ax * invd, ay * invd);
        __half2 o23 = __floats2half2_rn(az * invd, aw * invd);
        float2 ov;
        ((__half2*)&ov)[0] = o01;
        ((__half2*)&ov)[1] = o23;
        *(float2*)(&sT[wv][(r * 4 + grp) * TSTRIDE + cq * 4]) = ov;
    }
    __syncthreads();    // drains LDS writes

    // ---- GEMM phase ----
    int m = lane & 15, quad = lane >> 4;
    if (node0 < n) {
        const f16x8* wf = (const f16x8*)wfh;   // frag idx ((q*4+tt)*4+quad)*16+m

        int nodeA = node0 + m;
        if (nodeA >= n) nodeA = n - 1;         // tail-safe global loads

        const uint2* hrow8 = (const uint2*)(hr_in + (size_t)nodeA * 16);
        uint2 rlo = hrow8[quad];               // channels quad*8 .. +7
        uint2 rhi = hrow8[4 + quad];           // channels 32+quad*8 .. +7
        f16x8 af[4];
        af[0] = *(const f16x8*)(&sT[wv][m * TSTRIDE + quad * 8]);
        af[1] = *(const f16x8*)(&sT[wv][m * TSTRIDE + 32 + quad * 8]);
        {
            int cb = quad * 8;
            f32x2 q0 = __builtin_amdgcn_cvt_pk_f32_fp8(rlo.x, false);
            f32x2 q1 = __builtin_amdgcn_cvt_pk_f32_fp8(rlo.x, true);
            f32x2 q2 = __builtin_amdgcn_cvt_pk_f32_fp8(rlo.y, false);
            f32x2 q3 = __builtin_amdgcn_cvt_pk_f32_fp8(rlo.y, true);
            f16x8 a2;
            a2[0] = (_Float16)fmaxf(fmaf(q0[0], ssc[cb+0], ssh[cb+0]), 0.f);
            a2[1] = (_Float16)fmaxf(fmaf(q0[1], ssc[cb+1], ssh[cb+1]), 0.f);
            a2[2] = (_Float16)fmaxf(fmaf(q1[0], ssc[cb+2], ssh[cb+2]), 0.f);
            a2[3] = (_Float16)fmaxf(fmaf(q1[1], ssc[cb+3], ssh[cb+3]), 0.f);
            a2[4] = (_Float16)fmaxf(fmaf(q2[0], ssc[cb+4], ssh[cb+4]), 0.f);
            a2[5] = (_Float16)fmaxf(fmaf(q2[1], ssc[cb+5], ssh[cb+5]), 0.f);
            a2[6] = (_Float16)fmaxf(fmaf(q3[0], ssc[cb+6], ssh[cb+6]), 0.f);
            a2[7] = (_Float16)fmaxf(fmaf(q3[1], ssc[cb+7], ssh[cb+7]), 0.f);
            af[2] = a2;
            int cb3 = 32 + quad * 8;
            q0 = __builtin_amdgcn_cvt_pk_f32_fp8(rhi.x, false);
            q1 = __builtin_amdgcn_cvt_pk_f32_fp8(rhi.x, true);
            q2 = __builtin_amdgcn_cvt_pk_f32_fp8(rhi.y, false);
            q3 = __builtin_amdgcn_cvt_pk_f32_fp8(rhi.y, true);
            f16x8 a3;
            a3[0] = (_Float16)fmaxf(fmaf(q0[0], ssc[cb3+0], ssh[cb3+0]), 0.f);
            a3[1] = (_Float16)fmaxf(fmaf(q0[1], ssc[cb3+1], ssh[cb3+1]), 0.f);
            a3[2] = (_Float16)fmaxf(fmaf(q1[0], ssc[cb3+2], ssh[cb3+2]), 0.f);
            a3[3] = (_Float16)fmaxf(fmaf(q1[1], ssc[cb3+3], ssh[cb3+3]), 0.f);
            a3[4] = (_Float16)fmaxf(fmaf(q2[0], ssc[cb3+4], ssh[cb3+4]), 0.f);
            a3[5] = (_Float16)fmaxf(fmaf(q2[1], ssc[cb3+5], ssh[cb3+5]), 0.f);
            a3[6] = (_Float16)fmaxf(fmaf(q3[0], ssc[cb3+6], ssh[cb3+6]), 0.f);
            a3[7] = (_Float16)fmaxf(fmaf(q3[1], ssc[cb3+7], ssh[cb3+7]), 0.f);
            af[3] = a3;
        }

#pragma unroll
        for (int tt = 0; tt < 4; tt++) {
            float bv = bias[tt * 16 + m];
            f32x4 c = {bv, bv, bv, bv};
#pragma unroll
            for (int q = 0; q < 4; q++)
                c = __builtin_amdgcn_mfma_f32_16x16x32_f16(
                        af[q], wf[((q * 4 + tt) * 4 + quad) * 16 + m], c, 0, 0, 0);
            float s = 0.f, ss = 0.f;
#pragma unroll
            for (int r = 0; r < 4; r++) {
                int row = node0 + quad * 4 + r;
                float v = (row < n) ? c[r] : 0.f;
                if (row < n) {
                    int pb = __builtin_amdgcn_cvt_pk_fp8_f32(v, v, 0, false);
                    hr_out[(size_t)row * 64 + tt * 16 + m] = (unsigned char)(pb & 0xFF);
                }
                s += v;
                ss = fmaf(v, v, ss);
            }
            s  += __shfl_xor(s, 16, 64);  s  += __shfl_xor(s, 32, 64);
            ss += __shfl_xor(ss, 16, 64); ss += __shfl_xor(ss, 32, 64);
            if (quad == 0) {
                atomicAdd(&ls[tt * 16 + m], s);
                atomicAdd(&lss[tt * 16 + m], ss);
            }
        }
    }
    __syncthreads();
    if (t < 64) {
        float* slot = statsTmp + (size_t)(blockIdx.x & 63) * 128;
        unsafeAtomicAdd(&slot[t], ls[t]);
        unsafeAtomicAdd(&slot[64 + t], lss[t]);
    }
}

// ---- stats_reduce: fold 64 scratch slots into stats[128] ------------------
__global__ __launch_bounds__(128) void stats_reduce(const float* __restrict__ tmp,
                                                    float* __restrict__ stats)
{
    int t = threadIdx.x;       // 0..127
    float s = 0.f;
#pragma unroll 8
    for (int k = 0; k < 64; k++) s += tmp[k * 128 + t];
    stats[t] = s;
}

// ---- fused layer-3 BN+ReLU + attention pooling (fp8 raw input) -----------
__global__ __launch_bounds__(256) void bn_pool(
    const unsigned* __restrict__ h8, const float* __restrict__ stats,
    const float* __restrict__ g, const float* __restrict__ be,
    const float* __restrict__ x, const int* __restrict__ batch,
    float* __restrict__ rawpool, float invN, int N, int chunk)
{
    int wid  = blockIdx.x * 4 + (threadIdx.x >> 6);
    int lane = threadIdx.x & 63;
    int i0 = wid * chunk;
    if (i0 >= N) return;
    int i1 = min(i0 + chunk, N);

    float mu  = stats[lane] * invN;
    float var = stats[64 + lane] * invN - mu * mu;
    float sc  = g[lane] / sqrtf(var + EPS_BN);
    float sh  = fmaf(-mu, sc, be[lane]);

    int dw = lane >> 2, s3 = lane & 3;
    int   cur = batch[i0];
    float acc = 0.f;
    for (int i = i0; i < i1; i++) {
        int bi = batch[i];
        if (bi != cur) {
            unsafeAtomicAdd(&rawpool[cur * 64 + lane], acc);
            acc = 0.f;
            cur = bi;
        }
        float w = expf(x[(size_t)i * 6 + 4]);
        unsigned d = h8[(size_t)i * 16 + dw];
        f32x2 lo = __builtin_amdgcn_cvt_pk_f32_fp8(d, false);
        f32x2 hi = __builtin_amdgcn_cvt_pk_f32_fp8(d, true);
        float hv = (s3 == 0) ? lo[0] : (s3 == 1) ? lo[1] : (s3 == 2) ? hi[0] : hi[1];
        float v = fmaxf(fmaf(hv, sc, sh), 0.f);
        acc = fmaf(v, w, acc);
    }
    unsafeAtomicAdd(&rawpool[cur * 64 + lane], acc);
}

// ---- heads: normalize rawpool by 1/sumexp and counts, then 2 tiny MLPs ----
__global__ __launch_bounds__(64) void heads_kernel(
    const float* __restrict__ rawpool, const float* __restrict__ sumexp,
    const int* __restrict__ lb,
    const float* __restrict__ phW1, const float* __restrict__ phb1,
    const float* __restrict__ phW2, const float* __restrict__ phb2,
    const float* __restrict__ trW1, const float* __restrict__ trb1,
    const float* __restrict__ trW2, const float* __restrict__ trb2,
    float* __restrict__ out)
{
    int b = blockIdx.x, t = threadIdx.x;
    __shared__ float p[64], h1[32], h2[16];
    float cnt = (float)(lb[b + 1] - lb[b]);
    p[t] = rawpool[b * 64 + t] / (sumexp[0] * fmaxf(cnt, 1.0f));
    __syncthreads();
    if (t < 32) {
        float s = phb1[t];
        for (int k = 0; k < 64; k++) s = fmaf(p[k], phW1[k * 32 + t], s);
        h1[t] = fmaxf(s, 0.f);
    } else if (t < 48) {
        int tt = t - 32;
        float s = trb1[tt];
        for (int k = 0; k < 64; k++) s = fmaf(p[k], trW1[k * 16 + tt], s);
        h2[tt] = fmaxf(s, 0.f);
    }
    __syncthreads();
    if (t < 3) {
        float s = phb2[t];
        for (int k = 0; k < 32; k++) s = fmaf(h1[k], phW2[k * 3 + t], s);
        out[b * 3 + t] = s;
    } else if (t == 63) {
        float s = trb2[0];
        for (int k = 0; k < 16; k++) s = fmaf(h2[k], trW2[k], s);
        out[192 + b] = 1.0f / (1.0f + expf(-s));
    }
}

extern "C" void kernel_launch(void* const* d_in, const int* in_sizes, int n_in,
                              void* d_out, int out_size, void* d_ws, size_t ws_size,
                              hipStream_t stream)
{
    const float* x     = (const float*)d_in[0];
    const int*   ei    = (const int*)d_in[1];
    const int*   batch = (const int*)d_in[2];
    const float* W1l = (const float*)d_in[3];
    const float* b1  = (const float*)d_in[4];
    const float* W1r = (const float*)d_in[5];
    const float* W2l = (const float*)d_in[6];
    const float* b2  = (const float*)d_in[7];
    const float* W2r = (const float*)d_in[8];
    const float* W3l = (const float*)d_in[9];
    const float* b3  = (const float*)d_in[10];
    const float* W3r = (const float*)d_in[11];
    const float* g1  = (const float*)d_in[12];
    const float* be1 = (const float*)d_in[13];
    const float* g2  = (const float*)d_in[14];
    const float* be2 = (const float*)d_in[15];
    const float* g3  = (const float*)d_in[16];
    const float* be3 = (const float*)d_in[17];
    const float* phW1 = (const float*)d_in[18];
    const float* phb1 = (const float*)d_in[19];
    const float* phW2 = (const float*)d_in[20];
    const float* phb2 = (const float*)d_in[21];
    const float* trW1 = (const float*)d_in[22];
    const float* trb1 = (const float*)d_in[23];
    const float* trW2 = (const float*)d_in[24];
    const float* trb2 = (const float*)d_in[25];

    const int N = in_sizes[0] / 6;
    const int E = in_sizes[1] / 2;
    const int* src = ei;
    const int* dst = ei + E;

    const int NB    = (N + 255) >> 8;          // 391 buckets
    const int nBlkA = (E + EPB - 1) / EPB;     // 196 partition blocks

    float* ws = (float*)d_ws;
    const size_t N16 = (size_t)N * 16;
    unsigned* hr1   = (unsigned*)ws;               // N*16 dwords (fp8 raw h1)
    unsigned* hr2   = hr1 + N16;                   // N*16 (fp8 raw h2)
    unsigned* hr3   = hr2 + N16;                   // N*16 (fp8 raw h3)
    int*   epck     = (int*)(hr3 + N16);           // E packed src|dl<<24
    int*   eidx     = epck + E;                    // E (CSR by dst)
    int*   blockBin = eidx + E;                    // nBlkA * NBIN
    // --- contiguous zero region: binTotal + stats + statsTmp + rawpool + sumexp
    int*   binTotal = blockBin + (size_t)nBlkA * NBIN;   // NBIN
    float* stats    = (float*)(binTotal + NBIN);   // 3 * 128
    float* statsTmp = stats + 384;                 // 2 * 64 * 128
    float* rawpool  = statsTmp + 16384;            // 64*64
    float* sumexp   = rawpool + 4096;              // 1 (pad 4)
    // --- end zero region ---
    int*   binBase  = (int*)(sumexp + 4);          // NBIN + 1
    int*   rowptr   = binBase + NBIN + 1;          // N + 1
    int*   lb       = rowptr + N + 1;              // 65 (pad 72)
    __half* wfrag2  = (__half*)(lb + 72);          // 8192 fp16
    __half* wfrag3  = wfrag2 + 8192;               // 8192 fp16
    float* out      = (float*)d_out;

    const int mfmaBlocks = (N + 63) / 64;          // 1563 (4 x 16-node tiles/block)
    const size_t npair   = (size_t)N * 8;          // uint2 chunks of h-rows
    const int PBLK = 1024;                         // bn_pool blocks (4 waves each)
    const int chunk = (N + PBLK * 4 - 1) / (PBLK * 4);
    const float invN = 1.0f / (float)N;

    // ---- zero accumulators; merged prep+hist ----
    size_t zbytes = (char*)(sumexp + 4) - (char*)binTotal;
    hipMemsetAsync(binTotal, 0, zbytes, stream);
    prep_hist<<<nBlkA + 321, 256, 0, stream>>>(dst, blockBin, binTotal, E, nBlkA,
                                               x, sumexp, N, batch, lb,
                                               W2l, W2r, W3l, W3r, wfrag2, wfrag3);

    // ---- CSR build ----
    blockbin_offs<<<NBIN / 8, 512, 0, stream>>>(blockBin, binTotal, binBase,
                                                rowptr + N, nBlkA);
    bucket_scatter<<<nBlkA, 256, 0, stream>>>(src, dst, blockBin, epck, E);

    // ---- merged CSR-local + layer 1 (raw fp8 h1) ----
    csr_sage1<<<NB, 256, 0, stream>>>(epck, binBase, rowptr, eidx,
                                      x, W1l, b1, W1r, hr1, N);
    bn_stats<<<1024, 256, 0, stream>>>((const uint2*)hr1, stats, npair);

    // ---- layer 2: BN1-on-the-fly gather+GEMM -> raw fp8 h2; stats2 slots --
    agg_mm_mfma<<<mfmaBlocks, 256, 0, stream>>>(rowptr, eidx, hr1,
                                                stats, g1, be1, wfrag2, b2,
                                                (unsigned char*)hr2, statsTmp,
                                                invN, N);
    stats_reduce<<<1, 128, 0, stream>>>(statsTmp, stats + 128);

    // ---- layer 3: BN2-on-the-fly gather+GEMM -> raw fp8 h3; stats3 slots --
    agg_mm_mfma<<<mfmaBlocks, 256, 0, stream>>>(rowptr, eidx, hr2,
                                                stats + 128, g2, be2, wfrag3, b3,
                                                (unsigned char*)hr3,
                                                statsTmp + 8192, invN, N);
    stats_reduce<<<1, 128, 0, stream>>>(statsTmp + 8192, stats + 256);

    // ---- fused BN3 + attention pooling + heads ----
    bn_pool<<<PBLK, 256, 0, stream>>>(hr3, stats + 256, g3, be3,
                                      x, batch, rawpool, invN, N, chunk);
    heads_kernel<<<64, 64, 0, stream>>>(rawpool, sumexp, lb,
                                        phW1, phb1, phW2, phb2,
                                        trW1, trb1, trW2, trb2, out);
}

// Round 8
// 322.750 us; speedup vs baseline: 1.1078x; 1.0194x over previous
//
#include <hip/hip_runtime.h>
#include <hip/hip_fp16.h>
#include <cstdint>
#include <cstddef>

// ---------------------------------------------------------------------------
// TopoGNN: 3x SAGEConv(mean) + BN + ReLU, softmax-attention pooling, 2 heads.
// N=100000 nodes, E=1600000 edges, B=64 segments, IN_CH=6, HID=64.
// R5 (754us) bucket-CSR. R12 (474us) MFMA GEMM. R17/R19 (381us) fp8 gather.
// R20 (373us) agg fused into MFMA. R21 (361us) merges. R22 (357us) h fp16.
// R23 (766us REGR): per-block __threadfence evicts L2. Never fence gathers.
// R24 (341us): fence-free merges (prep+hist, csr+sage1).
// R25 (357us REGR): stats-prologue broadcast folds. Keep 1-block reduce.
// R26 (339us): h16-elim. R27 (329us): BN-on-the-fly, raw h fp8, bn_dual gone.
// R28: bn_stats pass DELETED — layer-1 stats computed in csr_sage1 from the
//     in-register fp32 acc (pre-quant, same as layers 2/3 do) via per-wave
//     shfl_xor tree -> ls/lss -> 64-slot statsTmp; 1-block stats_reduce
//     (SR1) folds slots. Replaces a 6.4MB-reading 1024-block pass.
// ---------------------------------------------------------------------------

#define EPB 8192   // edges per partition block (256 thr x 32)
#define NBIN 512   // padded bucket count (actual NB = ceil(N/256) <= 512)
#define EPS_BN 1e-5f

typedef _Float16 f16x8 __attribute__((ext_vector_type(8)));
typedef float    f32x4 __attribute__((ext_vector_type(4)));
typedef float    f32x2 __attribute__((ext_vector_type(2)));

// ---- merged: per-block bucket histogram (bid < nBlk) + prep roles --------
__global__ __launch_bounds__(256) void prep_hist(
    const int* __restrict__ dst, int* __restrict__ blockBin,
    int* __restrict__ binTotal, int E, int nBlk,
    const float* __restrict__ x, float* __restrict__ sumexp, int n,
    const int* __restrict__ batch, int* __restrict__ lb,
    const float* __restrict__ W2l, const float* __restrict__ W2r,
    const float* __restrict__ W3l, const float* __restrict__ W3r,
    __half* __restrict__ wfrag2, __half* __restrict__ wfrag3)
{
    __shared__ int hist[NBIN];
    __shared__ float wsum[4];
    int t = threadIdx.x;
    int bid = blockIdx.x;
    if (bid < nBlk) {
        for (int i = t; i < NBIN; i += 256) hist[i] = 0;
        __syncthreads();
        int e0 = bid * EPB;
#pragma unroll
        for (int k = 0; k < 32; k++) {
            int e = e0 + (k << 8) + t;
            if (e < E) atomicAdd(&hist[dst[e] >> 8], 1);
        }
        __syncthreads();
        for (int i = t; i < NBIN; i += 256) {
            int c = hist[i];
            blockBin[bid * NBIN + i] = c;
            if (c) atomicAdd(&binTotal[i], c);
        }
        return;
    }
    int pbid = bid - nBlk;
    if (pbid < 256) {
        float s = 0.f;
        int stride = 256 * 256;
        for (int i = pbid * 256 + t; i < n; i += stride)
            s += expf(x[(size_t)i * 6 + 4]);
#pragma unroll
        for (int o = 32; o > 0; o >>= 1) s += __shfl_down(s, o, 64);
        if ((t & 63) == 0) wsum[t >> 6] = s;
        __syncthreads();
        if (t == 0)
            unsafeAtomicAdd(sumexp, wsum[0] + wsum[1] + wsum[2] + wsum[3]);
    } else if (pbid == 256) {
        int b = t;
        if (b > 64) return;
        int lo = 0, hi = n;
        while (lo < hi) {
            int mid = (lo + hi) >> 1;
            if (batch[mid] < b) lo = mid + 1; else hi = mid;
        }
        lb[b] = lo;
    } else {
        bool second = (pbid >= 289);
        int i = (pbid - (second ? 289 : 257)) * 256 + t;
        if (i >= 8192) return;
        int j    = i & 7;
        int m    = (i >> 3) & 15;
        int quad = (i >> 7) & 3;
        int tt   = (i >> 9) & 3;
        int q    = i >> 11;
        int k    = (q & 1) * 32 + quad * 8 + j;
        int col  = tt * 16 + m;
        const float* W = second ? ((q < 2) ? W3l : W3r)
                                : ((q < 2) ? W2l : W2r);
        (second ? wfrag3 : wfrag2)[i] = __float2half_rn(W[k * 64 + col]);
    }
}

// ---- phase B: scan of bin totals + per-bin exclusive block-count scan ----
__global__ __launch_bounds__(512) void blockbin_offs(int* __restrict__ blockBin,
                                                     const int* __restrict__ binTotal,
                                                     int* __restrict__ binBase,
                                                     int* __restrict__ rowptrN,
                                                     int nBlk)
{
    __shared__ int s[NBIN];
    int t = threadIdx.x;
    int tot = binTotal[t];
    s[t] = tot;
    __syncthreads();
    for (int off = 1; off < NBIN; off <<= 1) {
        int v = (t >= off) ? s[t - off] : 0;
        __syncthreads();
        s[t] += v;
        __syncthreads();
    }
    int excl = s[t] - tot;
    if (blockIdx.x == 0) {
        binBase[t] = excl;
        if (t == NBIN - 1) { binBase[NBIN] = s[t]; *rowptrN = s[t]; }
    }
    __syncthreads();

    int wv   = t >> 6;              // 0..7
    int lane = t & 63;
    int bin  = blockIdx.x * 8 + wv;
    int carry = s[bin] - binTotal[bin];   // exclusive base for this bin
    for (int c0 = 0; c0 < nBlk; c0 += 64) {
        int blk = c0 + lane;
        int cnt = (blk < nBlk) ? blockBin[blk * NBIN + bin] : 0;
        int v = cnt;
#pragma unroll
        for (int d = 1; d < 64; d <<= 1) {
            int u = __shfl_up(v, d, 64);
            if (lane >= d) v += u;
        }
        if (blk < nBlk) blockBin[blk * NBIN + bin] = carry + v - cnt;
        carry += __shfl(v, 63, 64);
    }
}

// ---- phase C: place packed (src | local_dst<<24); per-block LDS cursors ---
__global__ __launch_bounds__(256) void bucket_scatter(const int* __restrict__ src,
                                                      const int* __restrict__ dst,
                                                      const int* __restrict__ blockBin,
                                                      int* __restrict__ epck, int E)
{
    __shared__ int cur[NBIN];
    int t = threadIdx.x;
    for (int i = t; i < NBIN; i += 256) cur[i] = blockBin[blockIdx.x * NBIN + i];
    __syncthreads();
    int e0 = blockIdx.x * EPB;
#pragma unroll
    for (int k = 0; k < 32; k++) {
        int e = e0 + (k << 8) + t;
        if (e < E) {
            int d = dst[e];
            int pos = atomicAdd(&cur[d >> 8], 1);
            epck[pos] = src[e] | ((d & 255) << 24);   // src < 2^24
        }
    }
}

// ---- merged phase D + layer 1 + layer-1 BN stats (R28) -------------------
__global__ __launch_bounds__(256) void csr_sage1(
    const int* __restrict__ epck, const int* __restrict__ binBase,
    int* __restrict__ rowptr, int* __restrict__ eidx,
    const float* __restrict__ x,
    const float* __restrict__ Wl, const float* __restrict__ bias,
    const float* __restrict__ Wr, unsigned* __restrict__ out,
    float* __restrict__ statsTmp, int N)
{
    __shared__ int cnt[256], s[256], cur[256];
    __shared__ float4 sWl[6 * 16];
    __shared__ float4 sWr[6 * 16];
    __shared__ float ls[64], lss[64];
    int t = threadIdx.x, bkt = blockIdx.x;
    for (int i = t; i < 6 * 16; i += 256) {
        sWl[i] = ((const float4*)Wl)[i];
        sWr[i] = ((const float4*)Wr)[i];
    }
    if (t < 64) { ls[t] = 0.f; lss[t] = 0.f; }
    int base = binBase[bkt], nE = binBase[bkt + 1] - base;
    cnt[t] = 0;
    __syncthreads();
    for (int j = t; j < nE; j += 256)
        atomicAdd(&cnt[(unsigned)epck[base + j] >> 24], 1);
    __syncthreads();
    s[t] = cnt[t];
    __syncthreads();
    for (int off = 1; off < 256; off <<= 1) {
        int v = (t >= off) ? s[t - off] : 0;
        __syncthreads();
        s[t] += v;
        __syncthreads();
    }
    int excl = s[t] - cnt[t];
    cur[t] = excl;
    int node = (bkt << 8) + t;
    bool valid = node < N;
    if (valid) rowptr[node] = base + excl;
    __syncthreads();
    for (int j = t; j < nE; j += 256) {
        int v = epck[base + j];
        int pos = atomicAdd(&cur[(unsigned)v >> 24], 1);
        eidx[base + pos] = v & 0xFFFFFF;     // contiguous 16KB span: stays in L2
    }
    __syncthreads();    // eidx writes drained to L2 before re-read; ls/lss init

    // ---- sage1 part: this block's nodes == this bucket (no early return;
    //      invalid nodes contribute zeros to the stats tree) ----
    int eb = base + excl, ee = base + s[t];   // empty for invalid nodes
    float a[6] = {0.f, 0.f, 0.f, 0.f, 0.f, 0.f};
    for (int j = eb; j < ee; j++) {
        int si = eidx[j];
        const float2* r = (const float2*)(x + (size_t)si * 6);
        float2 r0 = r[0], r1 = r[1], r2 = r[2];
        a[0] += r0.x; a[1] += r0.y; a[2] += r1.x;
        a[3] += r1.y; a[4] += r2.x; a[5] += r2.y;
    }
    float invd = 1.0f / fmaxf((float)(ee - eb), 1.0f);

    int nodeX = valid ? node : 0;             // OOB-safe x read
    const float2* xr2 = (const float2*)(x + (size_t)nodeX * 6);
    float2 x0 = xr2[0], x1 = xr2[1], x2 = xr2[2];
    float hh[6] = {x0.x, x0.y, x1.x, x1.y, x2.x, x2.y};

    float4 acc[16];
#pragma unroll
    for (int cg = 0; cg < 16; cg++) acc[cg] = ((const float4*)bias)[cg];
#pragma unroll
    for (int k = 0; k < 6; k++) {
        float am = a[k] * invd;
        float hk = hh[k];
#pragma unroll
        for (int cg = 0; cg < 16; cg++) {
            float4 wl = sWl[k * 16 + cg];
            float4 wr = sWr[k * 16 + cg];
            acc[cg].x = fmaf(am, wl.x, fmaf(hk, wr.x, acc[cg].x));
            acc[cg].y = fmaf(am, wl.y, fmaf(hk, wr.y, acc[cg].y));
            acc[cg].z = fmaf(am, wl.z, fmaf(hk, wr.z, acc[cg].z));
            acc[cg].w = fmaf(am, wl.w, fmaf(hk, wr.w, acc[cg].w));
        }
    }
    if (valid) {
        unsigned px[16];
#pragma unroll
        for (int cg = 0; cg < 16; cg++) {
            float4 av = acc[cg];
            int p = __builtin_amdgcn_cvt_pk_fp8_f32(av.x, av.y, 0, false);
            p     = __builtin_amdgcn_cvt_pk_fp8_f32(av.z, av.w, p, true);
            px[cg] = (unsigned)p;
        }
        uint4* orow = (uint4*)(out + (size_t)node * 16);
        orow[0] = make_uint4(px[0],  px[1],  px[2],  px[3]);
        orow[1] = make_uint4(px[4],  px[5],  px[6],  px[7]);
        orow[2] = make_uint4(px[8],  px[9],  px[10], px[11]);
        orow[3] = make_uint4(px[12], px[13], px[14], px[15]);
    }

    // ---- layer-1 BN stats from in-register fp32 acc (pre-quant) ----
    int lane = t & 63;
    float msk = valid ? 1.f : 0.f;
#pragma unroll
    for (int cg = 0; cg < 16; cg++) {
        float4 av = acc[cg];
        float vv[4] = {av.x * msk, av.y * msk, av.z * msk, av.w * msk};
#pragma unroll
        for (int k = 0; k < 4; k++) {
            float v = vv[k], v2 = v * v;
#pragma unroll
            for (int o = 32; o > 0; o >>= 1) {
                v  += __shfl_xor(v,  o, 64);
                v2 += __shfl_xor(v2, o, 64);
            }
            if (lane == 0) {
                atomicAdd(&ls[cg * 4 + k], v);
                atomicAdd(&lss[cg * 4 + k], v2);
            }
        }
    }
    __syncthreads();
    if (t < 64) {
        float* slot = statsTmp + (size_t)(bkt & 63) * 128;
        unsafeAtomicAdd(&slot[t], ls[t]);
        unsafeAtomicAdd(&slot[64 + t], lss[t]);
    }
}

// ---- fused BN-on-the-fly aggregation + MFMA GEMM + BN stats --------------
#define TSTRIDE 72
__global__ __launch_bounds__(256) void agg_mm_mfma(
    const int* __restrict__ rowptr, const int* __restrict__ eidx,
    const unsigned* __restrict__ hr_in,
    const float* __restrict__ stats, const float* __restrict__ g,
    const float* __restrict__ be,
    const __half* __restrict__ wfh, const float* __restrict__ bias,
    unsigned char* __restrict__ hr_out, float* __restrict__ statsTmp,
    float invN, int n)
{
    __shared__ float ls[64], lss[64];
    __shared__ float ssc[64], ssh[64];
    __shared__ _Float16 sT[4][16 * TSTRIDE];   // 4 waves x 16 nodes x 64ch
    int t = threadIdx.x;
    if (t < 64) {
        ls[t] = 0.f; lss[t] = 0.f;
        float mu  = stats[t] * invN;
        float var = stats[64 + t] * invN - mu * mu;
        float sc  = g[t] / sqrtf(var + EPS_BN);
        ssc[t] = sc;
        ssh[t] = fmaf(-mu, sc, be[t]);
    }
    __syncthreads();   // ssc/ssh visible to all waves

    int wv = t >> 6, lane = t & 63;
    int node0 = (blockIdx.x * 4 + wv) * 16;

    // ---- gather phase (BN+relu applied per decoded value) ----
    int grp = lane >> 4, cq = lane & 15;
    float sc0 = ssc[4 * cq],     sh0 = ssh[4 * cq];
    float sc1 = ssc[4 * cq + 1], sh1 = ssh[4 * cq + 1];
    float sc2 = ssc[4 * cq + 2], sh2 = ssh[4 * cq + 2];
    float sc3 = ssc[4 * cq + 3], sh3 = ssh[4 * cq + 3];
#pragma unroll 1
    for (int r = 0; r < 4; r++) {
        int node = node0 + r * 4 + grp;
        int b = 0, e = 0;
        if (node < n) { b = rowptr[node]; e = rowptr[node + 1]; }

        float4 a0 = {0,0,0,0}, a1 = {0,0,0,0}, a2 = {0,0,0,0}, a3 = {0,0,0,0};
#define EDGE(S, ACC)                                                            \
        {                                                                       \
            unsigned r_ = hr_in[(size_t)(S) * 16 + cq];                         \
            f32x2 lo_ = __builtin_amdgcn_cvt_pk_f32_fp8(r_, false);             \
            f32x2 hi_ = __builtin_amdgcn_cvt_pk_f32_fp8(r_, true);              \
            ACC.x += fmaxf(fmaf(lo_[0], sc0, sh0), 0.f);                        \
            ACC.y += fmaxf(fmaf(lo_[1], sc1, sh1), 0.f);                        \
            ACC.z += fmaxf(fmaf(hi_[0], sc2, sh2), 0.f);                        \
            ACC.w += fmaxf(fmaf(hi_[1], sc3, sh3), 0.f);                        \
        }
        int j = b;
        for (; j + 4 <= e; j += 4) {
            int s0 = eidx[j], s1 = eidx[j + 1], s2 = eidx[j + 2], s3 = eidx[j + 3];
            EDGE(s0, a0) EDGE(s1, a1) EDGE(s2, a2) EDGE(s3, a3)
        }
        for (; j < e; j++) {
            int s = eidx[j];
            EDGE(s, a0)
        }
#undef EDGE
        float ax = a0.x + a1.x + a2.x + a3.x;
        float ay = a0.y + a1.y + a2.y + a3.y;
        float az = a0.z + a1.z + a2.z + a3.z;
        float aw = a0.w + a1.w + a2.w + a3.w;
        float invd = 1.0f / fmaxf((float)(e - b), 1.0f);
        __half2 o01 = __floats2half2_rn(ax * invd, ay * invd);
        __half2 o23 = __floats2half2_rn(az * invd, aw * invd);
        float2 ov;
        ((__half2*)&ov)[0] = o01;
        ((__half2*)&ov)[1] = o23;
        *(float2*)(&sT[wv][(r * 4 + grp) * TSTRIDE + cq * 4]) = ov;
    }
    __syncthreads();    // drains LDS writes

    // ---- GEMM phase ----
    int m = lane & 15, quad = lane >> 4;
    if (node0 < n) {
        const f16x8* wf = (const f16x8*)wfh;   // frag idx ((q*4+tt)*4+quad)*16+m

        int nodeA = node0 + m;
        if (nodeA >= n) nodeA = n - 1;         // tail-safe global loads

        const uint2* hrow8 = (const uint2*)(hr_in + (size_t)nodeA * 16);
        uint2 rlo = hrow8[quad];               // channels quad*8 .. +7
        uint2 rhi = hrow8[4 + quad];           // channels 32+quad*8 .. +7
        f16x8 af[4];
        af[0] = *(const f16x8*)(&sT[wv][m * TSTRIDE + quad * 8]);
        af[1] = *(const f16x8*)(&sT[wv][m * TSTRIDE + 32 + quad * 8]);
        {
            int cb = quad * 8;
            f32x2 q0 = __builtin_amdgcn_cvt_pk_f32_fp8(rlo.x, false);
            f32x2 q1 = __builtin_amdgcn_cvt_pk_f32_fp8(rlo.x, true);
            f32x2 q2 = __builtin_amdgcn_cvt_pk_f32_fp8(rlo.y, false);
            f32x2 q3 = __builtin_amdgcn_cvt_pk_f32_fp8(rlo.y, true);
            f16x8 a2;
            a2[0] = (_Float16)fmaxf(fmaf(q0[0], ssc[cb+0], ssh[cb+0]), 0.f);
            a2[1] = (_Float16)fmaxf(fmaf(q0[1], ssc[cb+1], ssh[cb+1]), 0.f);
            a2[2] = (_Float16)fmaxf(fmaf(q1[0], ssc[cb+2], ssh[cb+2]), 0.f);
            a2[3] = (_Float16)fmaxf(fmaf(q1[1], ssc[cb+3], ssh[cb+3]), 0.f);
            a2[4] = (_Float16)fmaxf(fmaf(q2[0], ssc[cb+4], ssh[cb+4]), 0.f);
            a2[5] = (_Float16)fmaxf(fmaf(q2[1], ssc[cb+5], ssh[cb+5]), 0.f);
            a2[6] = (_Float16)fmaxf(fmaf(q3[0], ssc[cb+6], ssh[cb+6]), 0.f);
            a2[7] = (_Float16)fmaxf(fmaf(q3[1], ssc[cb+7], ssh[cb+7]), 0.f);
            af[2] = a2;
            int cb3 = 32 + quad * 8;
            q0 = __builtin_amdgcn_cvt_pk_f32_fp8(rhi.x, false);
            q1 = __builtin_amdgcn_cvt_pk_f32_fp8(rhi.x, true);
            q2 = __builtin_amdgcn_cvt_pk_f32_fp8(rhi.y, false);
            q3 = __builtin_amdgcn_cvt_pk_f32_fp8(rhi.y, true);
            f16x8 a3;
            a3[0] = (_Float16)fmaxf(fmaf(q0[0], ssc[cb3+0], ssh[cb3+0]), 0.f);
            a3[1] = (_Float16)fmaxf(fmaf(q0[1], ssc[cb3+1], ssh[cb3+1]), 0.f);
            a3[2] = (_Float16)fmaxf(fmaf(q1[0], ssc[cb3+2], ssh[cb3+2]), 0.f);
            a3[3] = (_Float16)fmaxf(fmaf(q1[1], ssc[cb3+3], ssh[cb3+3]), 0.f);
            a3[4] = (_Float16)fmaxf(fmaf(q2[0], ssc[cb3+4], ssh[cb3+4]), 0.f);
            a3[5] = (_Float16)fmaxf(fmaf(q2[1], ssc[cb3+5], ssh[cb3+5]), 0.f);
            a3[6] = (_Float16)fmaxf(fmaf(q3[0], ssc[cb3+6], ssh[cb3+6]), 0.f);
            a3[7] = (_Float16)fmaxf(fmaf(q3[1], ssc[cb3+7], ssh[cb3+7]), 0.f);
            af[3] = a3;
        }

#pragma unroll
        for (int tt = 0; tt < 4; tt++) {
            float bv = bias[tt * 16 + m];
            f32x4 c = {bv, bv, bv, bv};
#pragma unroll
            for (int q = 0; q < 4; q++)
                c = __builtin_amdgcn_mfma_f32_16x16x32_f16(
                        af[q], wf[((q * 4 + tt) * 4 + quad) * 16 + m], c, 0, 0, 0);
            float s = 0.f, ss = 0.f;
#pragma unroll
            for (int r = 0; r < 4; r++) {
                int row = node0 + quad * 4 + r;
                float v = (row < n) ? c[r] : 0.f;
                if (row < n) {
                    int pb = __builtin_amdgcn_cvt_pk_fp8_f32(v, v, 0, false);
                    hr_out[(size_t)row * 64 + tt * 16 + m] = (unsigned char)(pb & 0xFF);
                }
                s += v;
                ss = fmaf(v, v, ss);
            }
            s  += __shfl_xor(s, 16, 64);  s  += __shfl_xor(s, 32, 64);
            ss += __shfl_xor(ss, 16, 64); ss += __shfl_xor(ss, 32, 64);
            if (quad == 0) {
                atomicAdd(&ls[tt * 16 + m], s);
                atomicAdd(&lss[tt * 16 + m], ss);
            }
        }
    }
    __syncthreads();
    if (t < 64) {
        float* slot = statsTmp + (size_t)(blockIdx.x & 63) * 128;
        unsafeAtomicAdd(&slot[t], ls[t]);
        unsafeAtomicAdd(&slot[64 + t], lss[t]);
    }
}

// ---- stats_reduce: fold 64 scratch slots into stats[128] ------------------
__global__ __launch_bounds__(128) void stats_reduce(const float* __restrict__ tmp,
                                                    float* __restrict__ stats)
{
    int t = threadIdx.x;       // 0..127
    float s = 0.f;
#pragma unroll 8
    for (int k = 0; k < 64; k++) s += tmp[k * 128 + t];
    stats[t] = s;
}

// ---- fused layer-3 BN+ReLU + attention pooling (fp8 raw input) -----------
__global__ __launch_bounds__(256) void bn_pool(
    const unsigned* __restrict__ h8, const float* __restrict__ stats,
    const float* __restrict__ g, const float* __restrict__ be,
    const float* __restrict__ x, const int* __restrict__ batch,
    float* __restrict__ rawpool, float invN, int N, int chunk)
{
    int wid  = blockIdx.x * 4 + (threadIdx.x >> 6);
    int lane = threadIdx.x & 63;
    int i0 = wid * chunk;
    if (i0 >= N) return;
    int i1 = min(i0 + chunk, N);

    float mu  = stats[lane] * invN;
    float var = stats[64 + lane] * invN - mu * mu;
    float sc  = g[lane] / sqrtf(var + EPS_BN);
    float sh  = fmaf(-mu, sc, be[lane]);

    int dw = lane >> 2, s3 = lane & 3;
    int   cur = batch[i0];
    float acc = 0.f;
    for (int i = i0; i < i1; i++) {
        int bi = batch[i];
        if (bi != cur) {
            unsafeAtomicAdd(&rawpool[cur * 64 + lane], acc);
            acc = 0.f;
            cur = bi;
        }
        float w = expf(x[(size_t)i * 6 + 4]);
        unsigned d = h8[(size_t)i * 16 + dw];
        f32x2 lo = __builtin_amdgcn_cvt_pk_f32_fp8(d, false);
        f32x2 hi = __builtin_amdgcn_cvt_pk_f32_fp8(d, true);
        float hv = (s3 == 0) ? lo[0] : (s3 == 1) ? lo[1] : (s3 == 2) ? hi[0] : hi[1];
        float v = fmaxf(fmaf(hv, sc, sh), 0.f);
        acc = fmaf(v, w, acc);
    }
    unsafeAtomicAdd(&rawpool[cur * 64 + lane], acc);
}

// ---- heads: normalize rawpool by 1/sumexp and counts, then 2 tiny MLPs ----
__global__ __launch_bounds__(64) void heads_kernel(
    const float* __restrict__ rawpool, const float* __restrict__ sumexp,
    const int* __restrict__ lb,
    const float* __restrict__ phW1, const float* __restrict__ phb1,
    const float* __restrict__ phW2, const float* __restrict__ phb2,
    const float* __restrict__ trW1, const float* __restrict__ trb1,
    const float* __restrict__ trW2, const float* __restrict__ trb2,
    float* __restrict__ out)
{
    int b = blockIdx.x, t = threadIdx.x;
    __shared__ float p[64], h1[32], h2[16];
    float cnt = (float)(lb[b + 1] - lb[b]);
    p[t] = rawpool[b * 64 + t] / (sumexp[0] * fmaxf(cnt, 1.0f));
    __syncthreads();
    if (t < 32) {
        float s = phb1[t];
        for (int k = 0; k < 64; k++) s = fmaf(p[k], phW1[k * 32 + t], s);
        h1[t] = fmaxf(s, 0.f);
    } else if (t < 48) {
        int tt = t - 32;
        float s = trb1[tt];
        for (int k = 0; k < 64; k++) s = fmaf(p[k], trW1[k * 16 + tt], s);
        h2[tt] = fmaxf(s, 0.f);
    }
    __syncthreads();
    if (t < 3) {
        float s = phb2[t];
        for (int k = 0; k < 32; k++) s = fmaf(h1[k], phW2[k * 3 + t], s);
        out[b * 3 + t] = s;
    } else if (t == 63) {
        float s = trb2[0];
        for (int k = 0; k < 16; k++) s = fmaf(h2[k], trW2[k], s);
        out[192 + b] = 1.0f / (1.0f + expf(-s));
    }
}

extern "C" void kernel_launch(void* const* d_in, const int* in_sizes, int n_in,
                              void* d_out, int out_size, void* d_ws, size_t ws_size,
                              hipStream_t stream)
{
    const float* x     = (const float*)d_in[0];
    const int*   ei    = (const int*)d_in[1];
    const int*   batch = (const int*)d_in[2];
    const float* W1l = (const float*)d_in[3];
    const float* b1  = (const float*)d_in[4];
    const float* W1r = (const float*)d_in[5];
    const float* W2l = (const float*)d_in[6];
    const float* b2  = (const float*)d_in[7];
    const float* W2r = (const float*)d_in[8];
    const float* W3l = (const float*)d_in[9];
    const float* b3  = (const float*)d_in[10];
    const float* W3r = (const float*)d_in[11];
    const float* g1  = (const float*)d_in[12];
    const float* be1 = (const float*)d_in[13];
    const float* g2  = (const float*)d_in[14];
    const float* be2 = (const float*)d_in[15];
    const float* g3  = (const float*)d_in[16];
    const float* be3 = (const float*)d_in[17];
    const float* phW1 = (const float*)d_in[18];
    const float* phb1 = (const float*)d_in[19];
    const float* phW2 = (const float*)d_in[20];
    const float* phb2 = (const float*)d_in[21];
    const float* trW1 = (const float*)d_in[22];
    const float* trb1 = (const float*)d_in[23];
    const float* trW2 = (const float*)d_in[24];
    const float* trb2 = (const float*)d_in[25];

    const int N = in_sizes[0] / 6;
    const int E = in_sizes[1] / 2;
    const int* src = ei;
    const int* dst = ei + E;

    const int NB    = (N + 255) >> 8;          // 391 buckets
    const int nBlkA = (E + EPB - 1) / EPB;     // 196 partition blocks

    float* ws = (float*)d_ws;
    const size_t N16 = (size_t)N * 16;
    unsigned* hr1   = (unsigned*)ws;               // N*16 dwords (fp8 raw h1)
    unsigned* hr2   = hr1 + N16;                   // N*16 (fp8 raw h2)
    unsigned* hr3   = hr2 + N16;                   // N*16 (fp8 raw h3)
    int*   epck     = (int*)(hr3 + N16);           // E packed src|dl<<24
    int*   eidx     = epck + E;                    // E (CSR by dst)
    int*   blockBin = eidx + E;                    // nBlkA * NBIN
    // --- contiguous zero region: binTotal + stats + statsTmp(3x) + rawpool
    //     + sumexp
    int*   binTotal = blockBin + (size_t)nBlkA * NBIN;   // NBIN
    float* stats    = (float*)(binTotal + NBIN);   // 3 * 128
    float* statsTmp = stats + 384;                 // 3 * 64 * 128
    float* rawpool  = statsTmp + 24576;            // 64*64
    float* sumexp   = rawpool + 4096;              // 1 (pad 4)
    // --- end zero region ---
    int*   binBase  = (int*)(sumexp + 4);          // NBIN + 1
    int*   rowptr   = binBase + NBIN + 1;          // N + 1
    int*   lb       = rowptr + N + 1;              // 65 (pad 72)
    __half* wfrag2  = (__half*)(lb + 72);          // 8192 fp16
    __half* wfrag3  = wfrag2 + 8192;               // 8192 fp16
    float* out      = (float*)d_out;

    const int mfmaBlocks = (N + 63) / 64;          // 1563 (4 x 16-node tiles/block)
    const int PBLK = 1024;                         // bn_pool blocks (4 waves each)
    const int chunk = (N + PBLK * 4 - 1) / (PBLK * 4);
    const float invN = 1.0f / (float)N;

    // ---- zero accumulators; merged prep+hist ----
    size_t zbytes = (char*)(sumexp + 4) - (char*)binTotal;
    hipMemsetAsync(binTotal, 0, zbytes, stream);
    prep_hist<<<nBlkA + 321, 256, 0, stream>>>(dst, blockBin, binTotal, E, nBlkA,
                                               x, sumexp, N, batch, lb,
                                               W2l, W2r, W3l, W3r, wfrag2, wfrag3);

    // ---- CSR build ----
    blockbin_offs<<<NBIN / 8, 512, 0, stream>>>(blockBin, binTotal, binBase,
                                                rowptr + N, nBlkA);
    bucket_scatter<<<nBlkA, 256, 0, stream>>>(src, dst, blockBin, epck, E);

    // ---- merged CSR-local + layer 1 (raw fp8 h1 + in-register stats1) ----
    csr_sage1<<<NB, 256, 0, stream>>>(epck, binBase, rowptr, eidx,
                                      x, W1l, b1, W1r, hr1,
                                      statsTmp + 16384, N);
    stats_reduce<<<1, 128, 0, stream>>>(statsTmp + 16384, stats);

    // ---- layer 2: BN1-on-the-fly gather+GEMM -> raw fp8 h2; stats2 slots --
    agg_mm_mfma<<<mfmaBlocks, 256, 0, stream>>>(rowptr, eidx, hr1,
                                                stats, g1, be1, wfrag2, b2,
                                                (unsigned char*)hr2, statsTmp,
                                                invN, N);
    stats_reduce<<<1, 128, 0, stream>>>(statsTmp, stats + 128);

    // ---- layer 3: BN2-on-the-fly gather+GEMM -> raw fp8 h3; stats3 slots --
    agg_mm_mfma<<<mfmaBlocks, 256, 0, stream>>>(rowptr, eidx, hr2,
                                                stats + 128, g2, be2, wfrag3, b3,
                                                (unsigned char*)hr3,
                                                statsTmp + 8192, invN, N);
    stats_reduce<<<1, 128, 0, stream>>>(statsTmp + 8192, stats + 256);

    // ---- fused BN3 + attention pooling + heads ----
    bn_pool<<<PBLK, 256, 0, stream>>>(hr3, stats + 256, g3, be3,
                                      x, batch, rawpool, invN, N, chunk);
    heads_kernel<<<64, 64, 0, stream>>>(rawpool, sumexp, lb,
                                        phW1, phb1, phW2, phb2,
                                        trW1, trb1, trW2, trb2, out);
}

// Round 9
// 300.793 us; speedup vs baseline: 1.1886x; 1.0730x over previous
//
#include <hip/hip_runtime.h>
#include <hip/hip_fp16.h>
#include <cstdint>
#include <cstddef>

// ---------------------------------------------------------------------------
// TopoGNN: 3x SAGEConv(mean) + BN + ReLU, softmax-attention pooling, 2 heads.
// N=100000 nodes, E=1600000 edges, B=64 segments, IN_CH=6, HID=64.
// R5 (754us) bucket-CSR. R12 (474us) MFMA GEMM. R17/R19 (381us) fp8 gather.
// R20 (373us) agg fused into MFMA. R21 (361us) merges. R22 (357us) h fp16.
// R23 (766us REGR): per-block __threadfence evicts L2. Never fence gathers.
// R24 (341us): fence-free merges (prep+hist, csr+sage1).
// R25 (357us REGR): stats-prologue broadcast folds. Keep 1-block reduce.
// R26 (339us): h16-elim. R27 (329us): BN-on-the-fly, raw h fp8, bn_dual gone.
// R28 (322.8us): bn_stats pass deleted, stats1 in csr_sage1 — but the
//     768-shfl/thread tree made csr_sage1 41->59us (latency-bound @15% occ).
// R29: stats1 reduction rebuilt: fp8 px rows staged in LDS [256][16] (16KB),
//     transpose-read (thread t: channel t&63 over node-group t>>6; 4-lane
//     broadcasts are conflict-free), decode via cvt_pk on shifted dword,
//     one LDS atomic per channel. ~6x fewer serial ops than the shfl tree.
//     Stats are post-quant (== R27 semantics, absmax-validated).
// ---------------------------------------------------------------------------

#define EPB 8192   // edges per partition block (256 thr x 32)
#define NBIN 512   // padded bucket count (actual NB = ceil(N/256) <= 512)
#define EPS_BN 1e-5f

typedef _Float16 f16x8 __attribute__((ext_vector_type(8)));
typedef float    f32x4 __attribute__((ext_vector_type(4)));
typedef float    f32x2 __attribute__((ext_vector_type(2)));

// ---- merged: per-block bucket histogram (bid < nBlk) + prep roles --------
__global__ __launch_bounds__(256) void prep_hist(
    const int* __restrict__ dst, int* __restrict__ blockBin,
    int* __restrict__ binTotal, int E, int nBlk,
    const float* __restrict__ x, float* __restrict__ sumexp, int n,
    const int* __restrict__ batch, int* __restrict__ lb,
    const float* __restrict__ W2l, const float* __restrict__ W2r,
    const float* __restrict__ W3l, const float* __restrict__ W3r,
    __half* __restrict__ wfrag2, __half* __restrict__ wfrag3)
{
    __shared__ int hist[NBIN];
    __shared__ float wsum[4];
    int t = threadIdx.x;
    int bid = blockIdx.x;
    if (bid < nBlk) {
        for (int i = t; i < NBIN; i += 256) hist[i] = 0;
        __syncthreads();
        int e0 = bid * EPB;
#pragma unroll
        for (int k = 0; k < 32; k++) {
            int e = e0 + (k << 8) + t;
            if (e < E) atomicAdd(&hist[dst[e] >> 8], 1);
        }
        __syncthreads();
        for (int i = t; i < NBIN; i += 256) {
            int c = hist[i];
            blockBin[bid * NBIN + i] = c;
            if (c) atomicAdd(&binTotal[i], c);
        }
        return;
    }
    int pbid = bid - nBlk;
    if (pbid < 256) {
        float s = 0.f;
        int stride = 256 * 256;
        for (int i = pbid * 256 + t; i < n; i += stride)
            s += expf(x[(size_t)i * 6 + 4]);
#pragma unroll
        for (int o = 32; o > 0; o >>= 1) s += __shfl_down(s, o, 64);
        if ((t & 63) == 0) wsum[t >> 6] = s;
        __syncthreads();
        if (t == 0)
            unsafeAtomicAdd(sumexp, wsum[0] + wsum[1] + wsum[2] + wsum[3]);
    } else if (pbid == 256) {
        int b = t;
        if (b > 64) return;
        int lo = 0, hi = n;
        while (lo < hi) {
            int mid = (lo + hi) >> 1;
            if (batch[mid] < b) lo = mid + 1; else hi = mid;
        }
        lb[b] = lo;
    } else {
        bool second = (pbid >= 289);
        int i = (pbid - (second ? 289 : 257)) * 256 + t;
        if (i >= 8192) return;
        int j    = i & 7;
        int m    = (i >> 3) & 15;
        int quad = (i >> 7) & 3;
        int tt   = (i >> 9) & 3;
        int q    = i >> 11;
        int k    = (q & 1) * 32 + quad * 8 + j;
        int col  = tt * 16 + m;
        const float* W = second ? ((q < 2) ? W3l : W3r)
                                : ((q < 2) ? W2l : W2r);
        (second ? wfrag3 : wfrag2)[i] = __float2half_rn(W[k * 64 + col]);
    }
}

// ---- phase B: scan of bin totals + per-bin exclusive block-count scan ----
__global__ __launch_bounds__(512) void blockbin_offs(int* __restrict__ blockBin,
                                                     const int* __restrict__ binTotal,
                                                     int* __restrict__ binBase,
                                                     int* __restrict__ rowptrN,
                                                     int nBlk)
{
    __shared__ int s[NBIN];
    int t = threadIdx.x;
    int tot = binTotal[t];
    s[t] = tot;
    __syncthreads();
    for (int off = 1; off < NBIN; off <<= 1) {
        int v = (t >= off) ? s[t - off] : 0;
        __syncthreads();
        s[t] += v;
        __syncthreads();
    }
    int excl = s[t] - tot;
    if (blockIdx.x == 0) {
        binBase[t] = excl;
        if (t == NBIN - 1) { binBase[NBIN] = s[t]; *rowptrN = s[t]; }
    }
    __syncthreads();

    int wv   = t >> 6;              // 0..7
    int lane = t & 63;
    int bin  = blockIdx.x * 8 + wv;
    int carry = s[bin] - binTotal[bin];   // exclusive base for this bin
    for (int c0 = 0; c0 < nBlk; c0 += 64) {
        int blk = c0 + lane;
        int cnt = (blk < nBlk) ? blockBin[blk * NBIN + bin] : 0;
        int v = cnt;
#pragma unroll
        for (int d = 1; d < 64; d <<= 1) {
            int u = __shfl_up(v, d, 64);
            if (lane >= d) v += u;
        }
        if (blk < nBlk) blockBin[blk * NBIN + bin] = carry + v - cnt;
        carry += __shfl(v, 63, 64);
    }
}

// ---- phase C: place packed (src | local_dst<<24); per-block LDS cursors ---
__global__ __launch_bounds__(256) void bucket_scatter(const int* __restrict__ src,
                                                      const int* __restrict__ dst,
                                                      const int* __restrict__ blockBin,
                                                      int* __restrict__ epck, int E)
{
    __shared__ int cur[NBIN];
    int t = threadIdx.x;
    for (int i = t; i < NBIN; i += 256) cur[i] = blockBin[blockIdx.x * NBIN + i];
    __syncthreads();
    int e0 = blockIdx.x * EPB;
#pragma unroll
    for (int k = 0; k < 32; k++) {
        int e = e0 + (k << 8) + t;
        if (e < E) {
            int d = dst[e];
            int pos = atomicAdd(&cur[d >> 8], 1);
            epck[pos] = src[e] | ((d & 255) << 24);   // src < 2^24
        }
    }
}

// ---- merged phase D + layer 1 + layer-1 BN stats (R29 transpose-read) ----
__global__ __launch_bounds__(256) void csr_sage1(
    const int* __restrict__ epck, const int* __restrict__ binBase,
    int* __restrict__ rowptr, int* __restrict__ eidx,
    const float* __restrict__ x,
    const float* __restrict__ Wl, const float* __restrict__ bias,
    const float* __restrict__ Wr, unsigned* __restrict__ out,
    float* __restrict__ statsTmp, int N)
{
    __shared__ int cnt[256], s[256], cur[256];
    __shared__ float4 sWl[6 * 16];
    __shared__ float4 sWr[6 * 16];
    __shared__ float ls[64], lss[64];
    __shared__ unsigned spx[256 * 16];   // 16KB: fp8 rows for stats transpose
    int t = threadIdx.x, bkt = blockIdx.x;
    for (int i = t; i < 6 * 16; i += 256) {
        sWl[i] = ((const float4*)Wl)[i];
        sWr[i] = ((const float4*)Wr)[i];
    }
    if (t < 64) { ls[t] = 0.f; lss[t] = 0.f; }
    int base = binBase[bkt], nE = binBase[bkt + 1] - base;
    cnt[t] = 0;
    __syncthreads();
    for (int j = t; j < nE; j += 256)
        atomicAdd(&cnt[(unsigned)epck[base + j] >> 24], 1);
    __syncthreads();
    s[t] = cnt[t];
    __syncthreads();
    for (int off = 1; off < 256; off <<= 1) {
        int v = (t >= off) ? s[t - off] : 0;
        __syncthreads();
        s[t] += v;
        __syncthreads();
    }
    int excl = s[t] - cnt[t];
    cur[t] = excl;
    int node = (bkt << 8) + t;
    bool valid = node < N;
    if (valid) rowptr[node] = base + excl;
    __syncthreads();
    for (int j = t; j < nE; j += 256) {
        int v = epck[base + j];
        int pos = atomicAdd(&cur[(unsigned)v >> 24], 1);
        eidx[base + pos] = v & 0xFFFFFF;     // contiguous 16KB span: stays in L2
    }
    __syncthreads();    // eidx writes drained to L2 before re-read; ls/lss init

    // ---- sage1 part: this block's nodes == this bucket (no early return) --
    int eb = base + excl, ee = base + s[t];   // empty for invalid nodes
    float a[6] = {0.f, 0.f, 0.f, 0.f, 0.f, 0.f};
    for (int j = eb; j < ee; j++) {
        int si = eidx[j];
        const float2* r = (const float2*)(x + (size_t)si * 6);
        float2 r0 = r[0], r1 = r[1], r2 = r[2];
        a[0] += r0.x; a[1] += r0.y; a[2] += r1.x;
        a[3] += r1.y; a[4] += r2.x; a[5] += r2.y;
    }
    float invd = 1.0f / fmaxf((float)(ee - eb), 1.0f);

    int nodeX = valid ? node : 0;             // OOB-safe x read
    const float2* xr2 = (const float2*)(x + (size_t)nodeX * 6);
    float2 x0 = xr2[0], x1 = xr2[1], x2 = xr2[2];
    float hh[6] = {x0.x, x0.y, x1.x, x1.y, x2.x, x2.y};

    float4 acc[16];
#pragma unroll
    for (int cg = 0; cg < 16; cg++) acc[cg] = ((const float4*)bias)[cg];
#pragma unroll
    for (int k = 0; k < 6; k++) {
        float am = a[k] * invd;
        float hk = hh[k];
#pragma unroll
        for (int cg = 0; cg < 16; cg++) {
            float4 wl = sWl[k * 16 + cg];
            float4 wr = sWr[k * 16 + cg];
            acc[cg].x = fmaf(am, wl.x, fmaf(hk, wr.x, acc[cg].x));
            acc[cg].y = fmaf(am, wl.y, fmaf(hk, wr.y, acc[cg].y));
            acc[cg].z = fmaf(am, wl.z, fmaf(hk, wr.z, acc[cg].z));
            acc[cg].w = fmaf(am, wl.w, fmaf(hk, wr.w, acc[cg].w));
        }
    }
    unsigned px[16];
#pragma unroll
    for (int cg = 0; cg < 16; cg++) {
        float4 av = acc[cg];
        int p = __builtin_amdgcn_cvt_pk_fp8_f32(av.x, av.y, 0, false);
        p     = __builtin_amdgcn_cvt_pk_fp8_f32(av.z, av.w, p, true);
        px[cg] = valid ? (unsigned)p : 0u;    // fp8 0x00 == +0.0 for stats
    }
    if (valid) {
        uint4* orow = (uint4*)(out + (size_t)node * 16);
        orow[0] = make_uint4(px[0],  px[1],  px[2],  px[3]);
        orow[1] = make_uint4(px[4],  px[5],  px[6],  px[7]);
        orow[2] = make_uint4(px[8],  px[9],  px[10], px[11]);
        orow[3] = make_uint4(px[12], px[13], px[14], px[15]);
    }
    // stage rows in LDS for the stats transpose
    {
        unsigned* row = &spx[t * 16];
#pragma unroll
        for (int cg = 0; cg < 16; cg++) row[cg] = px[cg];
    }
    __syncthreads();

    // ---- stats1 transpose-read: thread t = channel (t&63) x node-group ----
    {
        int c = t & 63, grp = t >> 6;
        int d = c >> 2, sh = (c & 3) * 8;
        float sv = 0.f, ssv = 0.f;
        const unsigned* col = &spx[(grp * 64) * 16 + d];
#pragma unroll 8
        for (int i = 0; i < 64; i++) {
            unsigned dw = col[i * 16];
            f32x2 p = __builtin_amdgcn_cvt_pk_f32_fp8(dw >> sh, false);
            float v = p[0];
            sv += v;
            ssv = fmaf(v, v, ssv);
        }
        atomicAdd(&ls[c], sv);
        atomicAdd(&lss[c], ssv);
    }
    __syncthreads();
    if (t < 64) {
        float* slot = statsTmp + (size_t)(bkt & 63) * 128;
        unsafeAtomicAdd(&slot[t], ls[t]);
        unsafeAtomicAdd(&slot[64 + t], lss[t]);
    }
}

// ---- fused BN-on-the-fly aggregation + MFMA GEMM + BN stats --------------
#define TSTRIDE 72
__global__ __launch_bounds__(256) void agg_mm_mfma(
    const int* __restrict__ rowptr, const int* __restrict__ eidx,
    const unsigned* __restrict__ hr_in,
    const float* __restrict__ stats, const float* __restrict__ g,
    const float* __restrict__ be,
    const __half* __restrict__ wfh, const float* __restrict__ bias,
    unsigned char* __restrict__ hr_out, float* __restrict__ statsTmp,
    float invN, int n)
{
    __shared__ float ls[64], lss[64];
    __shared__ float ssc[64], ssh[64];
    __shared__ _Float16 sT[4][16 * TSTRIDE];   // 4 waves x 16 nodes x 64ch
    int t = threadIdx.x;
    if (t < 64) {
        ls[t] = 0.f; lss[t] = 0.f;
        float mu  = stats[t] * invN;
        float var = stats[64 + t] * invN - mu * mu;
        float sc  = g[t] / sqrtf(var + EPS_BN);
        ssc[t] = sc;
        ssh[t] = fmaf(-mu, sc, be[t]);
    }
    __syncthreads();   // ssc/ssh visible to all waves

    int wv = t >> 6, lane = t & 63;
    int node0 = (blockIdx.x * 4 + wv) * 16;

    // ---- gather phase (BN+relu applied per decoded value) ----
    int grp = lane >> 4, cq = lane & 15;
    float sc0 = ssc[4 * cq],     sh0 = ssh[4 * cq];
    float sc1 = ssc[4 * cq + 1], sh1 = ssh[4 * cq + 1];
    float sc2 = ssc[4 * cq + 2], sh2 = ssh[4 * cq + 2];
    float sc3 = ssc[4 * cq + 3], sh3 = ssh[4 * cq + 3];
#pragma unroll 1
    for (int r = 0; r < 4; r++) {
        int node = node0 + r * 4 + grp;
        int b = 0, e = 0;
        if (node < n) { b = rowptr[node]; e = rowptr[node + 1]; }

        float4 a0 = {0,0,0,0}, a1 = {0,0,0,0}, a2 = {0,0,0,0}, a3 = {0,0,0,0};
#define EDGE(S, ACC)                                                            \
        {                                                                       \
            unsigned r_ = hr_in[(size_t)(S) * 16 + cq];                         \
            f32x2 lo_ = __builtin_amdgcn_cvt_pk_f32_fp8(r_, false);             \
            f32x2 hi_ = __builtin_amdgcn_cvt_pk_f32_fp8(r_, true);              \
            ACC.x += fmaxf(fmaf(lo_[0], sc0, sh0), 0.f);                        \
            ACC.y += fmaxf(fmaf(lo_[1], sc1, sh1), 0.f);                        \
            ACC.z += fmaxf(fmaf(hi_[0], sc2, sh2), 0.f);                        \
            ACC.w += fmaxf(fmaf(hi_[1], sc3, sh3), 0.f);                        \
        }
        int j = b;
        for (; j + 4 <= e; j += 4) {
            int s0 = eidx[j], s1 = eidx[j + 1], s2 = eidx[j + 2], s3 = eidx[j + 3];
            EDGE(s0, a0) EDGE(s1, a1) EDGE(s2, a2) EDGE(s3, a3)
        }
        for (; j < e; j++) {
            int s = eidx[j];
            EDGE(s, a0)
        }
#undef EDGE
        float ax = a0.x + a1.x + a2.x + a3.x;
        float ay = a0.y + a1.y + a2.y + a3.y;
        float az = a0.z + a1.z + a2.z + a3.z;
        float aw = a0.w + a1.w + a2.w + a3.w;
        float invd = 1.0f / fmaxf((float)(e - b), 1.0f);
        __half2 o01 = __floats2half2_rn(ax * invd, ay * invd);
        __half2 o23 = __floats2half2_rn(az * invd, aw * invd);
        float2 ov;
        ((__half2*)&ov)[0] = o01;
        ((__half2*)&ov)[1] = o23;
        *(float2*)(&sT[wv][(r * 4 + grp) * TSTRIDE + cq * 4]) = ov;
    }
    __syncthreads();    // drains LDS writes

    // ---- GEMM phase ----
    int m = lane & 15, quad = lane >> 4;
    if (node0 < n) {
        const f16x8* wf = (const f16x8*)wfh;   // frag idx ((q*4+tt)*4+quad)*16+m

        int nodeA = node0 + m;
        if (nodeA >= n) nodeA = n - 1;         // tail-safe global loads

        const uint2* hrow8 = (const uint2*)(hr_in + (size_t)nodeA * 16);
        uint2 rlo = hrow8[quad];               // channels quad*8 .. +7
        uint2 rhi = hrow8[4 + quad];           // channels 32+quad*8 .. +7
        f16x8 af[4];
        af[0] = *(const f16x8*)(&sT[wv][m * TSTRIDE + quad * 8]);
        af[1] = *(const f16x8*)(&sT[wv][m * TSTRIDE + 32 + quad * 8]);
        {
            int cb = quad * 8;
            f32x2 q0 = __builtin_amdgcn_cvt_pk_f32_fp8(rlo.x, false);
            f32x2 q1 = __builtin_amdgcn_cvt_pk_f32_fp8(rlo.x, true);
            f32x2 q2 = __builtin_amdgcn_cvt_pk_f32_fp8(rlo.y, false);
            f32x2 q3 = __builtin_amdgcn_cvt_pk_f32_fp8(rlo.y, true);
            f16x8 a2;
            a2[0] = (_Float16)fmaxf(fmaf(q0[0], ssc[cb+0], ssh[cb+0]), 0.f);
            a2[1] = (_Float16)fmaxf(fmaf(q0[1], ssc[cb+1], ssh[cb+1]), 0.f);
            a2[2] = (_Float16)fmaxf(fmaf(q1[0], ssc[cb+2], ssh[cb+2]), 0.f);
            a2[3] = (_Float16)fmaxf(fmaf(q1[1], ssc[cb+3], ssh[cb+3]), 0.f);
            a2[4] = (_Float16)fmaxf(fmaf(q2[0], ssc[cb+4], ssh[cb+4]), 0.f);
            a2[5] = (_Float16)fmaxf(fmaf(q2[1], ssc[cb+5], ssh[cb+5]), 0.f);
            a2[6] = (_Float16)fmaxf(fmaf(q3[0], ssc[cb+6], ssh[cb+6]), 0.f);
            a2[7] = (_Float16)fmaxf(fmaf(q3[1], ssc[cb+7], ssh[cb+7]), 0.f);
            af[2] = a2;
            int cb3 = 32 + quad * 8;
            q0 = __builtin_amdgcn_cvt_pk_f32_fp8(rhi.x, false);
            q1 = __builtin_amdgcn_cvt_pk_f32_fp8(rhi.x, true);
            q2 = __builtin_amdgcn_cvt_pk_f32_fp8(rhi.y, false);
            q3 = __builtin_amdgcn_cvt_pk_f32_fp8(rhi.y, true);
            f16x8 a3;
            a3[0] = (_Float16)fmaxf(fmaf(q0[0], ssc[cb3+0], ssh[cb3+0]), 0.f);
            a3[1] = (_Float16)fmaxf(fmaf(q0[1], ssc[cb3+1], ssh[cb3+1]), 0.f);
            a3[2] = (_Float16)fmaxf(fmaf(q1[0], ssc[cb3+2], ssh[cb3+2]), 0.f);
            a3[3] = (_Float16)fmaxf(fmaf(q1[1], ssc[cb3+3], ssh[cb3+3]), 0.f);
            a3[4] = (_Float16)fmaxf(fmaf(q2[0], ssc[cb3+4], ssh[cb3+4]), 0.f);
            a3[5] = (_Float16)fmaxf(fmaf(q2[1], ssc[cb3+5], ssh[cb3+5]), 0.f);
            a3[6] = (_Float16)fmaxf(fmaf(q3[0], ssc[cb3+6], ssh[cb3+6]), 0.f);
            a3[7] = (_Float16)fmaxf(fmaf(q3[1], ssc[cb3+7], ssh[cb3+7]), 0.f);
            af[3] = a3;
        }

#pragma unroll
        for (int tt = 0; tt < 4; tt++) {
            float bv = bias[tt * 16 + m];
            f32x4 c = {bv, bv, bv, bv};
#pragma unroll
            for (int q = 0; q < 4; q++)
                c = __builtin_amdgcn_mfma_f32_16x16x32_f16(
                        af[q], wf[((q * 4 + tt) * 4 + quad) * 16 + m], c, 0, 0, 0);
            float s = 0.f, ss = 0.f;
#pragma unroll
            for (int r = 0; r < 4; r++) {
                int row = node0 + quad * 4 + r;
                float v = (row < n) ? c[r] : 0.f;
                if (row < n) {
                    int pb = __builtin_amdgcn_cvt_pk_fp8_f32(v, v, 0, false);
                    hr_out[(size_t)row * 64 + tt * 16 + m] = (unsigned char)(pb & 0xFF);
                }
                s += v;
                ss = fmaf(v, v, ss);
            }
            s  += __shfl_xor(s, 16, 64);  s  += __shfl_xor(s, 32, 64);
            ss += __shfl_xor(ss, 16, 64); ss += __shfl_xor(ss, 32, 64);
            if (quad == 0) {
                atomicAdd(&ls[tt * 16 + m], s);
                atomicAdd(&lss[tt * 16 + m], ss);
            }
        }
    }
    __syncthreads();
    if (t < 64) {
        float* slot = statsTmp + (size_t)(blockIdx.x & 63) * 128;
        unsafeAtomicAdd(&slot[t], ls[t]);
        unsafeAtomicAdd(&slot[64 + t], lss[t]);
    }
}

// ---- stats_reduce: fold 64 scratch slots into stats[128] ------------------
__global__ __launch_bounds__(128) void stats_reduce(const float* __restrict__ tmp,
                                                    float* __restrict__ stats)
{
    int t = threadIdx.x;       // 0..127
    float s = 0.f;
#pragma unroll 8
    for (int k = 0; k < 64; k++) s += tmp[k * 128 + t];
    stats[t] = s;
}

// ---- fused layer-3 BN+ReLU + attention pooling (fp8 raw input) -----------
__global__ __launch_bounds__(256) void bn_pool(
    const unsigned* __restrict__ h8, const float* __restrict__ stats,
    const float* __restrict__ g, const float* __restrict__ be,
    const float* __restrict__ x, const int* __restrict__ batch,
    float* __restrict__ rawpool, float invN, int N, int chunk)
{
    int wid  = blockIdx.x * 4 + (threadIdx.x >> 6);
    int lane = threadIdx.x & 63;
    int i0 = wid * chunk;
    if (i0 >= N) return;
    int i1 = min(i0 + chunk, N);

    float mu  = stats[lane] * invN;
    float var = stats[64 + lane] * invN - mu * mu;
    float sc  = g[lane] / sqrtf(var + EPS_BN);
    float sh  = fmaf(-mu, sc, be[lane]);

    int dw = lane >> 2, s3 = lane & 3;
    int   cur = batch[i0];
    float acc = 0.f;
    for (int i = i0; i < i1; i++) {
        int bi = batch[i];
        if (bi != cur) {
            unsafeAtomicAdd(&rawpool[cur * 64 + lane], acc);
            acc = 0.f;
            cur = bi;
        }
        float w = expf(x[(size_t)i * 6 + 4]);
        unsigned d = h8[(size_t)i * 16 + dw];
        f32x2 lo = __builtin_amdgcn_cvt_pk_f32_fp8(d, false);
        f32x2 hi = __builtin_amdgcn_cvt_pk_f32_fp8(d, true);
        float hv = (s3 == 0) ? lo[0] : (s3 == 1) ? lo[1] : (s3 == 2) ? hi[0] : hi[1];
        float v = fmaxf(fmaf(hv, sc, sh), 0.f);
        acc = fmaf(v, w, acc);
    }
    unsafeAtomicAdd(&rawpool[cur * 64 + lane], acc);
}

// ---- heads: normalize rawpool by 1/sumexp and counts, then 2 tiny MLPs ----
__global__ __launch_bounds__(64) void heads_kernel(
    const float* __restrict__ rawpool, const float* __restrict__ sumexp,
    const int* __restrict__ lb,
    const float* __restrict__ phW1, const float* __restrict__ phb1,
    const float* __restrict__ phW2, const float* __restrict__ phb2,
    const float* __restrict__ trW1, const float* __restrict__ trb1,
    const float* __restrict__ trW2, const float* __restrict__ trb2,
    float* __restrict__ out)
{
    int b = blockIdx.x, t = threadIdx.x;
    __shared__ float p[64], h1[32], h2[16];
    float cnt = (float)(lb[b + 1] - lb[b]);
    p[t] = rawpool[b * 64 + t] / (sumexp[0] * fmaxf(cnt, 1.0f));
    __syncthreads();
    if (t < 32) {
        float s = phb1[t];
        for (int k = 0; k < 64; k++) s = fmaf(p[k], phW1[k * 32 + t], s);
        h1[t] = fmaxf(s, 0.f);
    } else if (t < 48) {
        int tt = t - 32;
        float s = trb1[tt];
        for (int k = 0; k < 64; k++) s = fmaf(p[k], trW1[k * 16 + tt], s);
        h2[tt] = fmaxf(s, 0.f);
    }
    __syncthreads();
    if (t < 3) {
        float s = phb2[t];
        for (int k = 0; k < 32; k++) s = fmaf(h1[k], phW2[k * 3 + t], s);
        out[b * 3 + t] = s;
    } else if (t == 63) {
        float s = trb2[0];
        for (int k = 0; k < 16; k++) s = fmaf(h2[k], trW2[k], s);
        out[192 + b] = 1.0f / (1.0f + expf(-s));
    }
}

extern "C" void kernel_launch(void* const* d_in, const int* in_sizes, int n_in,
                              void* d_out, int out_size, void* d_ws, size_t ws_size,
                              hipStream_t stream)
{
    const float* x     = (const float*)d_in[0];
    const int*   ei    = (const int*)d_in[1];
    const int*   batch = (const int*)d_in[2];
    const float* W1l = (const float*)d_in[3];
    const float* b1  = (const float*)d_in[4];
    const float* W1r = (const float*)d_in[5];
    const float* W2l = (const float*)d_in[6];
    const float* b2  = (const float*)d_in[7];
    const float* W2r = (const float*)d_in[8];
    const float* W3l = (const float*)d_in[9];
    const float* b3  = (const float*)d_in[10];
    const float* W3r = (const float*)d_in[11];
    const float* g1  = (const float*)d_in[12];
    const float* be1 = (const float*)d_in[13];
    const float* g2  = (const float*)d_in[14];
    const float* be2 = (const float*)d_in[15];
    const float* g3  = (const float*)d_in[16];
    const float* be3 = (const float*)d_in[17];
    const float* phW1 = (const float*)d_in[18];
    const float* phb1 = (const float*)d_in[19];
    const float* phW2 = (const float*)d_in[20];
    const float* phb2 = (const float*)d_in[21];
    const float* trW1 = (const float*)d_in[22];
    const float* trb1 = (const float*)d_in[23];
    const float* trW2 = (const float*)d_in[24];
    const float* trb2 = (const float*)d_in[25];

    const int N = in_sizes[0] / 6;
    const int E = in_sizes[1] / 2;
    const int* src = ei;
    const int* dst = ei + E;

    const int NB    = (N + 255) >> 8;          // 391 buckets
    const int nBlkA = (E + EPB - 1) / EPB;     // 196 partition blocks

    float* ws = (float*)d_ws;
    const size_t N16 = (size_t)N * 16;
    unsigned* hr1   = (unsigned*)ws;               // N*16 dwords (fp8 raw h1)
    unsigned* hr2   = hr1 + N16;                   // N*16 (fp8 raw h2)
    unsigned* hr3   = hr2 + N16;                   // N*16 (fp8 raw h3)
    int*   epck     = (int*)(hr3 + N16);           // E packed src|dl<<24
    int*   eidx     = epck + E;                    // E (CSR by dst)
    int*   blockBin = eidx + E;                    // nBlkA * NBIN
    // --- contiguous zero region: binTotal + stats + statsTmp(3x) + rawpool
    //     + sumexp
    int*   binTotal = blockBin + (size_t)nBlkA * NBIN;   // NBIN
    float* stats    = (float*)(binTotal + NBIN);   // 3 * 128
    float* statsTmp = stats + 384;                 // 3 * 64 * 128
    float* rawpool  = statsTmp + 24576;            // 64*64
    float* sumexp   = rawpool + 4096;              // 1 (pad 4)
    // --- end zero region ---
    int*   binBase  = (int*)(sumexp + 4);          // NBIN + 1
    int*   rowptr   = binBase + NBIN + 1;          // N + 1
    int*   lb       = rowptr + N + 1;              // 65 (pad 72)
    __half* wfrag2  = (__half*)(lb + 72);          // 8192 fp16
    __half* wfrag3  = wfrag2 + 8192;               // 8192 fp16
    float* out      = (float*)d_out;

    const int mfmaBlocks = (N + 63) / 64;          // 1563 (4 x 16-node tiles/block)
    const int PBLK = 1024;                         // bn_pool blocks (4 waves each)
    const int chunk = (N + PBLK * 4 - 1) / (PBLK * 4);
    const float invN = 1.0f / (float)N;

    // ---- zero accumulators; merged prep+hist ----
    size_t zbytes = (char*)(sumexp + 4) - (char*)binTotal;
    hipMemsetAsync(binTotal, 0, zbytes, stream);
    prep_hist<<<nBlkA + 321, 256, 0, stream>>>(dst, blockBin, binTotal, E, nBlkA,
                                               x, sumexp, N, batch, lb,
                                               W2l, W2r, W3l, W3r, wfrag2, wfrag3);

    // ---- CSR build ----
    blockbin_offs<<<NBIN / 8, 512, 0, stream>>>(blockBin, binTotal, binBase,
                                                rowptr + N, nBlkA);
    bucket_scatter<<<nBlkA, 256, 0, stream>>>(src, dst, blockBin, epck, E);

    // ---- merged CSR-local + layer 1 (raw fp8 h1 + transpose-read stats1) --
    csr_sage1<<<NB, 256, 0, stream>>>(epck, binBase, rowptr, eidx,
                                      x, W1l, b1, W1r, hr1,
                                      statsTmp + 16384, N);
    stats_reduce<<<1, 128, 0, stream>>>(statsTmp + 16384, stats);

    // ---- layer 2: BN1-on-the-fly gather+GEMM -> raw fp8 h2; stats2 slots --
    agg_mm_mfma<<<mfmaBlocks, 256, 0, stream>>>(rowptr, eidx, hr1,
                                                stats, g1, be1, wfrag2, b2,
                                                (unsigned char*)hr2, statsTmp,
                                                invN, N);
    stats_reduce<<<1, 128, 0, stream>>>(statsTmp, stats + 128);

    // ---- layer 3: BN2-on-the-fly gather+GEMM -> raw fp8 h3; stats3 slots --
    agg_mm_mfma<<<mfmaBlocks, 256, 0, stream>>>(rowptr, eidx, hr2,
                                                stats + 128, g2, be2, wfrag3, b3,
                                                (unsigned char*)hr3,
                                                statsTmp + 8192, invN, N);
    stats_reduce<<<1, 128, 0, stream>>>(statsTmp + 8192, stats + 256);

    // ---- fused BN3 + attention pooling + heads ----
    bn_pool<<<PBLK, 256, 0, stream>>>(hr3, stats + 256, g3, be3,
                                      x, batch, rawpool, invN, N, chunk);
    heads_kernel<<<64, 64, 0, stream>>>(rawpool, sumexp, lb,
                                        phW1, phb1, phW2, phb2,
                                        trW1, trb1, trW2, trb2, out);
}